// Round 21
// baseline (77.542 us; speedup 1.0000x reference)
//
#include <hip/hip_runtime.h>
#include <hip/hip_bf16.h>

#define D 128
#define H 256
#define NB 32
#define NN 128

typedef __attribute__((ext_vector_type(8))) _Float16 f16x8;
typedef __attribute__((ext_vector_type(4))) float f32x4;
typedef __attribute__((ext_vector_type(16))) float f32x16;
typedef __attribute__((ext_vector_type(4))) unsigned int uint4v;

__device__ __forceinline__ unsigned short to_f16u(float f) {
  _Float16 h = (_Float16)f;
  return __builtin_bit_cast(unsigned short, h);
}

// packed f32x2 -> f16x2: v_cvt_pkrtz_f16_f32 (verified R17)
__device__ __forceinline__ unsigned cvt_pk_f16(float lo, float hi) {
  unsigned d;
  asm("v_cvt_pkrtz_f16_f32 %0, %1, %2" : "=v"(d) : "v"(lo), "v"(hi));
  return d;
}

// packed f16 add (verified R17); v_pk_add_bf16 does NOT exist (R10)
__device__ __forceinline__ unsigned pk_add_f16(unsigned a, unsigned b) {
  unsigned d;
  asm("v_pk_add_f16 %0, %1, %2" : "=v"(d) : "v"(a), "v"(b));
  return d;
}

// packed relu: signed-i16 max with 0 (verified R7-R17)
__device__ __forceinline__ unsigned pk_relu(unsigned x) {
  unsigned d;
  asm("v_pk_max_i16 %0, %1, %2" : "=v"(d) : "v"(x), "v"(0u));
  return d;
}

// ---------------- Kernel 0: repack all weights to f16 MFMA B-fragment order ----
__global__ __launch_bounds__(512) void k_repack(
    const float* __restrict__ mw1, const float* __restrict__ uw1,
    const float* __restrict__ uw2, const float* __restrict__ mw2,
    unsigned short* __restrict__ w1f, unsigned short* __restrict__ w3f,
    unsigned short* __restrict__ w4f, unsigned short* __restrict__ bw2) {
  const int gt = blockIdx.x * 512 + threadIdx.x;
  const int tile = gt >> 6, l = gt & 63;
  const int lg = l >> 4, l15 = l & 15;
  if (tile < 128) {
    const int ks = tile >> 5, ntg = tile & 31;
#pragma unroll
    for (int e = 0; e < 8; ++e) {
      int k = ks * 32 + lg * 8 + e;
      int col = ntg * 16 + l15;
      float v = (col < 256) ? mw1[k * 256 + col] : mw1[(128 + k) * 256 + (col - 256)];
      w1f[(size_t)(tile * 64 + l) * 8 + e] = to_f16u(v);
    }
  } else if (tile < 256) {
    const int t = tile - 128, ks = t >> 4, ntg = t & 15;
#pragma unroll
    for (int e = 0; e < 8; ++e) {
      int k = ks * 32 + lg * 8 + e;
      w3f[(size_t)(t * 64 + l) * 8 + e] = to_f16u(uw1[k * 256 + ntg * 16 + l15]);
    }
  } else if (tile < 320) {
    const int t = tile - 256, ks = t >> 3, ntg = t & 7;
#pragma unroll
    for (int e = 0; e < 8; ++e) {
      int k = ks * 32 + lg * 8 + e;
      w4f[(size_t)(t * 64 + l) * 8 + e] = to_f16u(uw2[k * 128 + ntg * 16 + l15]);
    }
  } else {
    const int t = tile - 320;            // 0..63: st = t>>2, ntile = t&3
    const int st = t >> 2, ntile = t & 3;
    const int lh = l >> 5, l31 = l & 31;
#pragma unroll
    for (int e = 0; e < 8; ++e) {
      int k = st * 16 + lh * 8 + e;
      bw2[(size_t)(t * 64 + l) * 8 + e] = to_f16u(mw2[k * 128 + ntile * 32 + l31]);
    }
  }
}

// ---------------- Kernel 1: LN*mask -> f16 + projection GEMM via MFMA (R18) ----
__global__ __launch_bounds__(256) void k_ln_proj(
    const float* __restrict__ nodes, const float* __restrict__ node_mask,
    const float* __restrict__ ln_g, const float* __restrict__ ln_b,
    const unsigned short* __restrict__ w1f,
    float* __restrict__ xi_p, unsigned short* __restrict__ xjh) {
  const int row0 = blockIdx.x * 16;
  const int half = blockIdx.y;
  const int tid = threadIdx.x;
  __shared__ unsigned short xh[16 * 128];   // f16, 16B-group swizzled

  {
    const int r = tid >> 4, l16 = tid & 15, d0 = l16 * 8;
    float4 v0 = *(const float4*)(nodes + (size_t)(row0 + r) * D + d0);
    float4 v1 = *(const float4*)(nodes + (size_t)(row0 + r) * D + d0 + 4);
    float s1 = v0.x + v0.y + v0.z + v0.w + v1.x + v1.y + v1.z + v1.w;
    float s2 = v0.x * v0.x + v0.y * v0.y + v0.z * v0.z + v0.w * v0.w +
               v1.x * v1.x + v1.y * v1.y + v1.z * v1.z + v1.w * v1.w;
#pragma unroll
    for (int off = 1; off < 16; off <<= 1) {
      s1 += __shfl_xor(s1, off);
      s2 += __shfl_xor(s2, off);
    }
    float mu = s1 * (1.0f / 128.0f);
    float var = s2 * (1.0f / 128.0f) - mu * mu;
    float rsig = rsqrtf(var + 1e-5f);
    float m = node_mask[row0 + r];
    float4 g0 = *(const float4*)(ln_g + d0), g1 = *(const float4*)(ln_g + d0 + 4);
    float4 b0 = *(const float4*)(ln_b + d0), b1 = *(const float4*)(ln_b + d0 + 4);
    float x0 = ((v0.x - mu) * rsig * g0.x + b0.x) * m;
    float x1 = ((v0.y - mu) * rsig * g0.y + b0.y) * m;
    float x2 = ((v0.z - mu) * rsig * g0.z + b0.z) * m;
    float x3 = ((v0.w - mu) * rsig * g0.w + b0.w) * m;
    float x4 = ((v1.x - mu) * rsig * g1.x + b1.x) * m;
    float x5 = ((v1.y - mu) * rsig * g1.y + b1.y) * m;
    float x6 = ((v1.z - mu) * rsig * g1.z + b1.z) * m;
    float x7 = ((v1.w - mu) * rsig * g1.w + b1.w) * m;
    uint4v u;
    u[0] = cvt_pk_f16(x0, x1); u[1] = cvt_pk_f16(x2, x3);
    u[2] = cvt_pk_f16(x4, x5); u[3] = cvt_pk_f16(x6, x7);
    const int g = l16 ^ (r & 7);          // swizzled 16B-group index
    *(uint4v*)(&xh[r * 128 + g * 8]) = u;
  }
  __syncthreads();

  const int w = tid >> 6, l = tid & 63;
  const int lg = l >> 4, l15 = l & 15;
  f32x4 acc[4];
#pragma unroll
  for (int nt = 0; nt < 4; ++nt) acc[nt] = (f32x4){0.f, 0.f, 0.f, 0.f};

#pragma unroll
  for (int ks = 0; ks < 4; ++ks) {
    const int g = (ks * 4 + lg) ^ (l15 & 7);
    f16x8 a = *(const f16x8*)(&xh[l15 * 128 + g * 8]);
#pragma unroll
    for (int nt = 0; nt < 4; ++nt) {
      const int tile = ks * 32 + half * 16 + w * 4 + nt;
      f16x8 bf = *(const f16x8*)(w1f + (size_t)(tile * 64 + l) * 8);
      acc[nt] = __builtin_amdgcn_mfma_f32_16x16x32_f16(a, bf, acc[nt], 0, 0, 0);
    }
  }

  if (half == 0) {
#pragma unroll
    for (int nt = 0; nt < 4; ++nt)
#pragma unroll
      for (int r = 0; r < 4; ++r)
        xi_p[(size_t)(row0 + lg * 4 + r) * H + w * 64 + nt * 16 + l15] = acc[nt][r];
  } else {
#pragma unroll
    for (int nt = 0; nt < 4; ++nt)
#pragma unroll
      for (int r = 0; r < 4; ++r)
        xjh[(size_t)(row0 + lg * 4 + r) * H + w * 64 + nt * 16 + l15] = to_f16u(acc[nt][r]);
  }
}

// ---------------- Kernel 2: msgs GEMM, 32x32x16, xjh ALSO staged in LDS --------
// R21: R20 structure + xjs (full 128 j x 256 k, 64 KB) in LDS, written in
// fragment-tile order [(jslab*16+st)*2+lh][32 j] so xu ds_reads are
// conflict-free. Block LDS ~134 KB -> 1 block/CU; launch_bounds(512,2) lifts
// the reg cap 128 -> 256 so the compiler can pipeline the now-all-LDS chain
// (ds_read 12cy vs L2 200cy). This is the decisive chain-length experiment:
// R13/R15/R17/R20 falsified phase-lock/occupancy/VALU/LDS-BW theories.
// Spill tripwire: WRITE_SIZE ~2MB.
__global__ __launch_bounds__(512, 2) void k_msgs(
    const float* __restrict__ xi_p, const unsigned short* __restrict__ xjh,
    const unsigned short* __restrict__ bw2g, const float* __restrict__ mb1,
    const float* __restrict__ mb2, const float* __restrict__ node_mask,
    float* __restrict__ agg) {
  const int b = blockIdx.y;
  const int i0 = blockIdx.x * 2;
  const int tid = threadIdx.x;           // 0..511
  const int w = tid >> 6, l = tid & 63;  // 8 waves
  const int jslab = w >> 1;              // 0..3: 32-row j-slab
  const int nh = w & 1;                  // 0..1: 64-col n-half
  const int jbase = jslab * 32;
  const int l31 = l & 31, lh = l >> 5;

  __shared__ unsigned short bw2s[32768]; // 64 KB B fragments (64 tiles x 1KB)
  __shared__ unsigned short xjs[32768];  // 64 KB xjh fragments (128 tiles... 4096 x 16B)
  __shared__ unsigned cs2[2][128];       // f16-pair (xi_p + mb1), per i
  __shared__ float mb2s[128], maskS[128];
  __shared__ float waveAgg[8][2][64];

  {
    const uint4v* src = (const uint4v*)bw2g;
    uint4v* dst = (uint4v*)bw2s;
#pragma unroll
    for (int c = 0; c < 8; ++c) dst[c * 512 + tid] = src[c * 512 + tid];
  }
  {
    // Stage xjh[b] (128 j x 256 k f16) into fragment-tile order:
    // 16B-chunk index = ((js*16 + st)*2 + lh)*32 + (j&31), st = c>>1, lh = c&1.
    const int jj = tid & 127;            // row
    const int qq = tid >> 7;             // 0..3 -> chunks qq*8 .. qq*8+7
    const int js = jj >> 5, j31 = jj & 31;
    const unsigned short* grow = xjh + (size_t)(b * NN + jj) * H;
    uint4v* dst = (uint4v*)xjs;
#pragma unroll
    for (int r = 0; r < 8; ++r) {
      const int c = qq * 8 + r;          // 0..31
      const int st = c >> 1, lhh = c & 1;
      dst[((js * 16 + st) * 2 + lhh) * 32 + j31] =
          *(const uint4v*)(grow + c * 8);
    }
  }
  if (tid < 256) {
    int ii = tid >> 7, p = tid & 127;
    float2 xi2 = *(const float2*)(xi_p + (size_t)(b * NN + i0 + ii) * H + 2 * p);
    float2 mbv = *(const float2*)(mb1 + 2 * p);
    cs2[ii][p] = cvt_pk_f16(xi2.x + mbv.x, xi2.y + mbv.y);
  }
  if (tid < 128) { mb2s[tid] = mb2[tid]; maskS[tid] = node_mask[b * NN + tid]; }
  __syncthreads();

  f32x16 acc[2][2];                      // [i][ntile]
#pragma unroll
  for (int ii = 0; ii < 2; ++ii)
#pragma unroll
    for (int nt = 0; nt < 2; ++nt)
#pragma unroll
      for (int r = 0; r < 16; ++r) acc[ii][nt][r] = 0.f;

  const uint4v* bfrag = (const uint4v*)bw2s;
  const uint4v* xfrag = (const uint4v*)xjs;

#pragma unroll
  for (int st = 0; st < 16; ++st) {
    const int kb = st * 16 + lh * 8;     // f16-elem k offset
    uint4v xu = xfrag[((jslab * 16 + st) * 2 + lh) * 32 + l31];
    uint4v cc0 = *(const uint4v*)(&cs2[0][kb >> 1]);
    uint4v cc1 = *(const uint4v*)(&cs2[1][kb >> 1]);
    uint4v a0, a1;
#pragma unroll
    for (int p = 0; p < 4; ++p) {
      a0[p] = pk_relu(pk_add_f16(xu[p], cc0[p]));
      a1[p] = pk_relu(pk_add_f16(xu[p], cc1[p]));
    }
    f16x8 af0 = __builtin_bit_cast(f16x8, a0);
    f16x8 af1 = __builtin_bit_cast(f16x8, a1);
#pragma unroll
    for (int nt = 0; nt < 2; ++nt) {
      f16x8 bf = __builtin_bit_cast(f16x8, bfrag[(st * 4 + nh * 2 + nt) * 64 + l]);
      acc[0][nt] = __builtin_amdgcn_mfma_f32_32x32x16_f16(af0, bf, acc[0][nt], 0, 0, 0);
      acc[1][nt] = __builtin_amdgcn_mfma_f32_32x32x16_f16(af1, bf, acc[1][nt], 0, 0, 0);
    }
  }

  // Epilogue: relu(acc+mb2)*mask_j, column-sum over the tile's 32 j rows.
#pragma unroll
  for (int ii = 0; ii < 2; ++ii)
#pragma unroll
    for (int nt = 0; nt < 2; ++nt) {
      const float bias = mb2s[nh * 64 + nt * 32 + l31];
      float s = 0.f;
#pragma unroll
      for (int reg = 0; reg < 16; ++reg) {
        const int j = jbase + 4 * lh + (reg & 3) + 8 * (reg >> 2);
        s = fmaf(fmaxf(acc[ii][nt][reg] + bias, 0.f), maskS[j], s);
      }
      s += __shfl_xor(s, 32);
      if (l < 32) waveAgg[w][ii][nt * 32 + l31] = s;
    }
  __syncthreads();
  if (tid < 256) {
    const int ii = tid >> 7, col = tid & 127;  // 2 i's x 128 cols
    const int nh2 = col >> 6, c6 = col & 63;
    agg[(size_t)(b * NN + i0 + ii) * D + col] =
        waveAgg[nh2][ii][c6] + waveAgg[2 + nh2][ii][c6] +
        waveAgg[4 + nh2][ii][c6] + waveAgg[6 + nh2][ii][c6];
  }
}

// ---------------- Kernel 3: update MLP via MFMA + residual + mask (R18) --------
__global__ __launch_bounds__(256) void k_upd(
    const float* __restrict__ nodes, const float* __restrict__ agg,
    const unsigned short* __restrict__ w3f, const float* __restrict__ ub1,
    const unsigned short* __restrict__ w4f, const float* __restrict__ ub2,
    const float* __restrict__ node_mask, float* __restrict__ out) {
  const int row0 = blockIdx.x * 16;
  const int tid = threadIdx.x;
  __shared__ unsigned short ah[16 * 256];  // f16 [16][32 groups], swizzled
  __shared__ unsigned short uh[16 * 256];  // f16 u, swizzled
  __shared__ float ns[16][128];
  __shared__ float msk[16];

  {
    const int r = tid >> 4, l16 = tid & 15, d0 = l16 * 8;
    float4 n0 = *(const float4*)(nodes + (size_t)(row0 + r) * D + d0);
    float4 n1 = *(const float4*)(nodes + (size_t)(row0 + r) * D + d0 + 4);
    *(float4*)(&ns[r][d0]) = n0;
    *(float4*)(&ns[r][d0 + 4]) = n1;
    uint4v u;
    u[0] = cvt_pk_f16(n0.x, n0.y); u[1] = cvt_pk_f16(n0.z, n0.w);
    u[2] = cvt_pk_f16(n1.x, n1.y); u[3] = cvt_pk_f16(n1.z, n1.w);
    int g = l16 ^ (r & 7);
    *(uint4v*)(&ah[r * 256 + g * 8]) = u;
    float4 a0 = *(const float4*)(agg + (size_t)(row0 + r) * D + d0);
    float4 a1 = *(const float4*)(agg + (size_t)(row0 + r) * D + d0 + 4);
    u[0] = cvt_pk_f16(a0.x, a0.y); u[1] = cvt_pk_f16(a0.z, a0.w);
    u[2] = cvt_pk_f16(a1.x, a1.y); u[3] = cvt_pk_f16(a1.z, a1.w);
    g = (16 + l16) ^ (r & 7);
    *(uint4v*)(&ah[r * 256 + g * 8]) = u;
    if (tid < 16) msk[tid] = node_mask[row0 + tid];
  }
  __syncthreads();

  const int w = tid >> 6, l = tid & 63;
  const int lg = l >> 4, l15 = l & 15;

  // GEMM1: 16 x 256, K=256
  f32x4 acc[4];
#pragma unroll
  for (int nt = 0; nt < 4; ++nt) acc[nt] = (f32x4){0.f, 0.f, 0.f, 0.f};
#pragma unroll
  for (int ks = 0; ks < 8; ++ks) {
    const int g = (ks * 4 + lg) ^ (l15 & 7);
    f16x8 a = *(const f16x8*)(&ah[l15 * 256 + g * 8]);
#pragma unroll
    for (int nt = 0; nt < 4; ++nt) {
      const int tile = ks * 16 + w * 4 + nt;
      f16x8 bf = *(const f16x8*)(w3f + (size_t)(tile * 64 + l) * 8);
      acc[nt] = __builtin_amdgcn_mfma_f32_16x16x32_f16(a, bf, acc[nt], 0, 0, 0);
    }
  }
  // u = relu(acc + ub1) -> uh (swizzled scalar stores)
#pragma unroll
  for (int nt = 0; nt < 4; ++nt) {
    const int col = w * 64 + nt * 16 + l15;
    const float bias = ub1[col];
#pragma unroll
    for (int r = 0; r < 4; ++r) {
      const int row = lg * 4 + r;
      const int g = (col >> 3) ^ (row & 7);
      uh[row * 256 + g * 8 + (col & 7)] = to_f16u(fmaxf(acc[nt][r] + bias, 0.f));
    }
  }
  __syncthreads();

  // GEMM2: 16 x 128, K=256
  f32x4 acc2[2];
  acc2[0] = (f32x4){0.f, 0.f, 0.f, 0.f};
  acc2[1] = (f32x4){0.f, 0.f, 0.f, 0.f};
#pragma unroll
  for (int ks = 0; ks < 8; ++ks) {
    const int g = (ks * 4 + lg) ^ (l15 & 7);
    f16x8 a = *(const f16x8*)(&uh[l15 * 256 + g * 8]);
#pragma unroll
    for (int nt = 0; nt < 2; ++nt) {
      const int tile = ks * 8 + w * 2 + nt;
      f16x8 bf = *(const f16x8*)(w4f + (size_t)(tile * 64 + l) * 8);
      acc2[nt] = __builtin_amdgcn_mfma_f32_16x16x32_f16(a, bf, acc2[nt], 0, 0, 0);
    }
  }
#pragma unroll
  for (int nt = 0; nt < 2; ++nt) {
    const int col = w * 32 + nt * 16 + l15;
    const float ub2v = ub2[col];
#pragma unroll
    for (int r = 0; r < 4; ++r) {
      const int row = lg * 4 + r;
      out[(size_t)(row0 + row) * D + col] =
          (ns[row][col] + acc2[nt][r] + ub2v) * msk[row];
    }
  }
}

extern "C" void kernel_launch(void* const* d_in, const int* in_sizes, int n_in,
                              void* d_out, int out_size, void* d_ws, size_t ws_size,
                              hipStream_t stream) {
  (void)in_sizes; (void)n_in; (void)out_size; (void)ws_size;
  const float* nodes     = (const float*)d_in[0];
  const float* node_mask = (const float*)d_in[1];
  const float* ln_g      = (const float*)d_in[2];
  const float* ln_b      = (const float*)d_in[3];
  const float* mw1       = (const float*)d_in[4];
  const float* mb1       = (const float*)d_in[5];
  const float* mw2       = (const float*)d_in[6];
  const float* mb2       = (const float*)d_in[7];
  const float* uw1       = (const float*)d_in[8];
  const float* ub1       = (const float*)d_in[9];
  const float* uw2       = (const float*)d_in[10];
  const float* ub2       = (const float*)d_in[11];
  float* out = (float*)d_out;

  char* ws = (char*)d_ws;
  float*          xi_p = (float*)(ws);                               // 4 MB
  unsigned short* xjh  = (unsigned short*)(ws + ((size_t)4 << 20));  // 2 MB
  float*          agg  = (float*)(ws + ((size_t)6 << 20));           // 2 MB
  unsigned short* bw2  = (unsigned short*)(ws + ((size_t)8 << 20));            // 64 KB
  unsigned short* w1f  = (unsigned short*)(ws + ((size_t)8 << 20) + (64 << 10));   // 128 KB
  unsigned short* w3f  = (unsigned short*)(ws + ((size_t)8 << 20) + (192 << 10));  // 128 KB
  unsigned short* w4f  = (unsigned short*)(ws + ((size_t)8 << 20) + (320 << 10));  // 64 KB

  k_repack<<<48, 512, 0, stream>>>(mw1, uw1, uw2, mw2, w1f, w3f, w4f, bw2);
  k_ln_proj<<<dim3(256, 2), 256, 0, stream>>>(nodes, node_mask, ln_g, ln_b, w1f, xi_p, xjh);
  k_msgs<<<dim3(NN / 2, NB), 512, 0, stream>>>(xi_p, xjh, bw2, mb1, mb2, node_mask, agg);
  k_upd<<<256, 256, 0, stream>>>(nodes, agg, w3f, ub1, w4f, ub2, node_mask, out);
}

// Round 22
// 64.935 us; speedup vs baseline: 1.1942x; 1.1942x over previous
//
#include <hip/hip_runtime.h>
#include <hip/hip_bf16.h>

#define D 128
#define H 256
#define NB 32
#define NN 128

typedef __attribute__((ext_vector_type(8))) _Float16 f16x8;
typedef __attribute__((ext_vector_type(4))) float f32x4;
typedef __attribute__((ext_vector_type(16))) float f32x16;
typedef __attribute__((ext_vector_type(4))) unsigned int uint4v;

__device__ __forceinline__ unsigned short to_f16u(float f) {
  _Float16 h = (_Float16)f;
  return __builtin_bit_cast(unsigned short, h);
}

// packed f32x2 -> f16x2: v_cvt_pkrtz_f16_f32 (verified R17)
__device__ __forceinline__ unsigned cvt_pk_f16(float lo, float hi) {
  unsigned d;
  asm("v_cvt_pkrtz_f16_f32 %0, %1, %2" : "=v"(d) : "v"(lo), "v"(hi));
  return d;
}

// packed f16 add (verified R17); v_pk_add_bf16 does NOT exist (R10)
__device__ __forceinline__ unsigned pk_add_f16(unsigned a, unsigned b) {
  unsigned d;
  asm("v_pk_add_f16 %0, %1, %2" : "=v"(d) : "v"(a), "v"(b));
  return d;
}

// packed relu: signed-i16 max with 0 (verified R7-R17)
__device__ __forceinline__ unsigned pk_relu(unsigned x) {
  unsigned d;
  asm("v_pk_max_i16 %0, %1, %2" : "=v"(d) : "v"(x), "v"(0u));
  return d;
}

// ---------------- Kernel 0: repack all weights to f16 MFMA B-fragment order ----
__global__ __launch_bounds__(512) void k_repack(
    const float* __restrict__ mw1, const float* __restrict__ uw1,
    const float* __restrict__ uw2, const float* __restrict__ mw2,
    unsigned short* __restrict__ w1f, unsigned short* __restrict__ w3f,
    unsigned short* __restrict__ w4f, unsigned short* __restrict__ bw2) {
  const int gt = blockIdx.x * 512 + threadIdx.x;
  const int tile = gt >> 6, l = gt & 63;
  const int lg = l >> 4, l15 = l & 15;
  if (tile < 128) {
    const int ks = tile >> 5, ntg = tile & 31;
#pragma unroll
    for (int e = 0; e < 8; ++e) {
      int k = ks * 32 + lg * 8 + e;
      int col = ntg * 16 + l15;
      float v = (col < 256) ? mw1[k * 256 + col] : mw1[(128 + k) * 256 + (col - 256)];
      w1f[(size_t)(tile * 64 + l) * 8 + e] = to_f16u(v);
    }
  } else if (tile < 256) {
    const int t = tile - 128, ks = t >> 4, ntg = t & 15;
#pragma unroll
    for (int e = 0; e < 8; ++e) {
      int k = ks * 32 + lg * 8 + e;
      w3f[(size_t)(t * 64 + l) * 8 + e] = to_f16u(uw1[k * 256 + ntg * 16 + l15]);
    }
  } else if (tile < 320) {
    const int t = tile - 256, ks = t >> 3, ntg = t & 7;
#pragma unroll
    for (int e = 0; e < 8; ++e) {
      int k = ks * 32 + lg * 8 + e;
      w4f[(size_t)(t * 64 + l) * 8 + e] = to_f16u(uw2[k * 128 + ntg * 16 + l15]);
    }
  } else {
    const int t = tile - 320;            // 0..63: st = t>>2, ntile = t&3
    const int st = t >> 2, ntile = t & 3;
    const int lh = l >> 5, l31 = l & 31;
#pragma unroll
    for (int e = 0; e < 8; ++e) {
      int k = st * 16 + lh * 8 + e;
      bw2[(size_t)(t * 64 + l) * 8 + e] = to_f16u(mw2[k * 128 + ntile * 32 + l31]);
    }
  }
}

// ---------------- Kernel 1: LN*mask -> f16 + projection GEMM via MFMA (R18) ----
__global__ __launch_bounds__(256) void k_ln_proj(
    const float* __restrict__ nodes, const float* __restrict__ node_mask,
    const float* __restrict__ ln_g, const float* __restrict__ ln_b,
    const unsigned short* __restrict__ w1f,
    float* __restrict__ xi_p, unsigned short* __restrict__ xjh) {
  const int row0 = blockIdx.x * 16;
  const int half = blockIdx.y;
  const int tid = threadIdx.x;
  __shared__ unsigned short xh[16 * 128];   // f16, 16B-group swizzled

  {
    const int r = tid >> 4, l16 = tid & 15, d0 = l16 * 8;
    float4 v0 = *(const float4*)(nodes + (size_t)(row0 + r) * D + d0);
    float4 v1 = *(const float4*)(nodes + (size_t)(row0 + r) * D + d0 + 4);
    float s1 = v0.x + v0.y + v0.z + v0.w + v1.x + v1.y + v1.z + v1.w;
    float s2 = v0.x * v0.x + v0.y * v0.y + v0.z * v0.z + v0.w * v0.w +
               v1.x * v1.x + v1.y * v1.y + v1.z * v1.z + v1.w * v1.w;
#pragma unroll
    for (int off = 1; off < 16; off <<= 1) {
      s1 += __shfl_xor(s1, off);
      s2 += __shfl_xor(s2, off);
    }
    float mu = s1 * (1.0f / 128.0f);
    float var = s2 * (1.0f / 128.0f) - mu * mu;
    float rsig = rsqrtf(var + 1e-5f);
    float m = node_mask[row0 + r];
    float4 g0 = *(const float4*)(ln_g + d0), g1 = *(const float4*)(ln_g + d0 + 4);
    float4 b0 = *(const float4*)(ln_b + d0), b1 = *(const float4*)(ln_b + d0 + 4);
    float x0 = ((v0.x - mu) * rsig * g0.x + b0.x) * m;
    float x1 = ((v0.y - mu) * rsig * g0.y + b0.y) * m;
    float x2 = ((v0.z - mu) * rsig * g0.z + b0.z) * m;
    float x3 = ((v0.w - mu) * rsig * g0.w + b0.w) * m;
    float x4 = ((v1.x - mu) * rsig * g1.x + b1.x) * m;
    float x5 = ((v1.y - mu) * rsig * g1.y + b1.y) * m;
    float x6 = ((v1.z - mu) * rsig * g1.z + b1.z) * m;
    float x7 = ((v1.w - mu) * rsig * g1.w + b1.w) * m;
    uint4v u;
    u[0] = cvt_pk_f16(x0, x1); u[1] = cvt_pk_f16(x2, x3);
    u[2] = cvt_pk_f16(x4, x5); u[3] = cvt_pk_f16(x6, x7);
    const int g = l16 ^ (r & 7);          // swizzled 16B-group index
    *(uint4v*)(&xh[r * 128 + g * 8]) = u;
  }
  __syncthreads();

  const int w = tid >> 6, l = tid & 63;
  const int lg = l >> 4, l15 = l & 15;
  f32x4 acc[4];
#pragma unroll
  for (int nt = 0; nt < 4; ++nt) acc[nt] = (f32x4){0.f, 0.f, 0.f, 0.f};

#pragma unroll
  for (int ks = 0; ks < 4; ++ks) {
    const int g = (ks * 4 + lg) ^ (l15 & 7);
    f16x8 a = *(const f16x8*)(&xh[l15 * 128 + g * 8]);
#pragma unroll
    for (int nt = 0; nt < 4; ++nt) {
      const int tile = ks * 32 + half * 16 + w * 4 + nt;
      f16x8 bf = *(const f16x8*)(w1f + (size_t)(tile * 64 + l) * 8);
      acc[nt] = __builtin_amdgcn_mfma_f32_16x16x32_f16(a, bf, acc[nt], 0, 0, 0);
    }
  }

  if (half == 0) {
#pragma unroll
    for (int nt = 0; nt < 4; ++nt)
#pragma unroll
      for (int r = 0; r < 4; ++r)
        xi_p[(size_t)(row0 + lg * 4 + r) * H + w * 64 + nt * 16 + l15] = acc[nt][r];
  } else {
#pragma unroll
    for (int nt = 0; nt < 4; ++nt)
#pragma unroll
      for (int r = 0; r < 4; ++r)
        xjh[(size_t)(row0 + lg * 4 + r) * H + w * 64 + nt * 16 + l15] = to_f16u(acc[nt][r]);
  }
}

// ---------------- Kernel 2: msgs GEMM, 32x32x16, all-LDS, 1024-thr block -------
// R22 = R21's all-LDS chain at R20's occupancy: 1024 thr (16 waves) / 4 i's
// per block -> 1 block/CU but 16 waves/CU = 4 waves/SIMD (same as R20).
// Wave w: ipair = w>>3, jslab = (w&7)>>1, nh = w&1; computes 2 i's of its
// ipair. xu from xjs LDS (12cy) instead of L2 (200cy) -- the clean chain A/B
// R21 confounded with occupancy. Reg cap 128; R21 measured 88 VGPR for this
// loop -> ~40 slack for pipelining. Spill tripwire: WRITE ~2MB.
__global__ __launch_bounds__(1024, 4) void k_msgs(
    const float* __restrict__ xi_p, const unsigned short* __restrict__ xjh,
    const unsigned short* __restrict__ bw2g, const float* __restrict__ mb1,
    const float* __restrict__ mb2, const float* __restrict__ node_mask,
    float* __restrict__ agg) {
  const int b = blockIdx.y;
  const int i0 = blockIdx.x * 4;
  const int tid = threadIdx.x;           // 0..1023
  const int w = tid >> 6, l = tid & 63;  // 16 waves
  const int ipair = w >> 3;              // 0..1
  const int jslab = (w & 7) >> 1;        // 0..3
  const int nh = w & 1;                  // 0..1
  const int jbase = jslab * 32;
  const int l31 = l & 31, lh = l >> 5;

  __shared__ unsigned short bw2s[32768]; // 64 KB B fragments
  __shared__ unsigned short xjs[32768];  // 64 KB xjh fragments (4096 x 16B)
  __shared__ unsigned cs2[4][128];       // f16-pair (xi_p + mb1), per i
  __shared__ float mb2s[128], maskS[128];
  __shared__ float waveAgg[16][2][64];

  {
    const uint4v* src = (const uint4v*)bw2g;
    uint4v* dst = (uint4v*)bw2s;
#pragma unroll
    for (int c = 0; c < 4; ++c) dst[c * 1024 + tid] = src[c * 1024 + tid];
  }
  {
    // Stage xjh[b] (128 j x 256 k f16) into fragment-tile order:
    // chunk index = ((js*16 + st)*2 + lh)*32 + (j&31); st = c>>1, lh = c&1.
    const int jj = tid & 127;
    const int qq = tid >> 7;             // 0..7 -> chunks qq*4 .. qq*4+3
    const int js = jj >> 5, j31 = jj & 31;
    const unsigned short* grow = xjh + (size_t)(b * NN + jj) * H;
    uint4v* dst = (uint4v*)xjs;
#pragma unroll
    for (int r = 0; r < 4; ++r) {
      const int c = qq * 4 + r;          // 0..31
      const int st = c >> 1, lhh = c & 1;
      dst[((js * 16 + st) * 2 + lhh) * 32 + j31] =
          *(const uint4v*)(grow + c * 8);
    }
  }
  if (tid < 512) {
    int ii = tid >> 7, p = tid & 127;    // 4 i's x 128 pairs
    float2 xi2 = *(const float2*)(xi_p + (size_t)(b * NN + i0 + ii) * H + 2 * p);
    float2 mbv = *(const float2*)(mb1 + 2 * p);
    cs2[ii][p] = cvt_pk_f16(xi2.x + mbv.x, xi2.y + mbv.y);
  }
  if (tid < 128) { mb2s[tid] = mb2[tid]; maskS[tid] = node_mask[b * NN + tid]; }
  __syncthreads();

  f32x16 acc[2][2];                      // [i-of-pair][ntile]
#pragma unroll
  for (int ii = 0; ii < 2; ++ii)
#pragma unroll
    for (int nt = 0; nt < 2; ++nt)
#pragma unroll
      for (int r = 0; r < 16; ++r) acc[ii][nt][r] = 0.f;

  const uint4v* bfrag = (const uint4v*)bw2s;
  const uint4v* xfrag = (const uint4v*)xjs;

#pragma unroll
  for (int st = 0; st < 16; ++st) {
    const int kb = st * 16 + lh * 8;     // f16-elem k offset
    uint4v xu = xfrag[((jslab * 16 + st) * 2 + lh) * 32 + l31];
    uint4v cc0 = *(const uint4v*)(&cs2[ipair * 2 + 0][kb >> 1]);
    uint4v cc1 = *(const uint4v*)(&cs2[ipair * 2 + 1][kb >> 1]);
    uint4v a0, a1;
#pragma unroll
    for (int p = 0; p < 4; ++p) {
      a0[p] = pk_relu(pk_add_f16(xu[p], cc0[p]));
      a1[p] = pk_relu(pk_add_f16(xu[p], cc1[p]));
    }
    f16x8 af0 = __builtin_bit_cast(f16x8, a0);
    f16x8 af1 = __builtin_bit_cast(f16x8, a1);
#pragma unroll
    for (int nt = 0; nt < 2; ++nt) {
      f16x8 bf = __builtin_bit_cast(f16x8, bfrag[(st * 4 + nh * 2 + nt) * 64 + l]);
      acc[0][nt] = __builtin_amdgcn_mfma_f32_32x32x16_f16(af0, bf, acc[0][nt], 0, 0, 0);
      acc[1][nt] = __builtin_amdgcn_mfma_f32_32x32x16_f16(af1, bf, acc[1][nt], 0, 0, 0);
    }
  }

  // Epilogue: relu(acc+mb2)*mask_j, column-sum over the tile's 32 j rows.
#pragma unroll
  for (int ii = 0; ii < 2; ++ii)
#pragma unroll
    for (int nt = 0; nt < 2; ++nt) {
      const float bias = mb2s[nh * 64 + nt * 32 + l31];
      float s = 0.f;
#pragma unroll
      for (int reg = 0; reg < 16; ++reg) {
        const int j = jbase + 4 * lh + (reg & 3) + 8 * (reg >> 2);
        s = fmaf(fmaxf(acc[ii][nt][reg] + bias, 0.f), maskS[j], s);
      }
      s += __shfl_xor(s, 32);
      if (l < 32) waveAgg[w][ii][nt * 32 + l31] = s;
    }
  __syncthreads();
  if (tid < 512) {
    const int ii4 = tid >> 7, col = tid & 127;  // 4 i's x 128 cols
    const int ipq = ii4 >> 1, iwi = ii4 & 1;
    const int nh2 = col >> 6, c6 = col & 63;
    agg[(size_t)(b * NN + i0 + ii4) * D + col] =
        waveAgg[ipq * 8 + 0 + nh2][iwi][c6] + waveAgg[ipq * 8 + 2 + nh2][iwi][c6] +
        waveAgg[ipq * 8 + 4 + nh2][iwi][c6] + waveAgg[ipq * 8 + 6 + nh2][iwi][c6];
  }
}

// ---------------- Kernel 3: update MLP via MFMA + residual + mask (R18) --------
__global__ __launch_bounds__(256) void k_upd(
    const float* __restrict__ nodes, const float* __restrict__ agg,
    const unsigned short* __restrict__ w3f, const float* __restrict__ ub1,
    const unsigned short* __restrict__ w4f, const float* __restrict__ ub2,
    const float* __restrict__ node_mask, float* __restrict__ out) {
  const int row0 = blockIdx.x * 16;
  const int tid = threadIdx.x;
  __shared__ unsigned short ah[16 * 256];  // f16 [16][32 groups], swizzled
  __shared__ unsigned short uh[16 * 256];  // f16 u, swizzled
  __shared__ float ns[16][128];
  __shared__ float msk[16];

  {
    const int r = tid >> 4, l16 = tid & 15, d0 = l16 * 8;
    float4 n0 = *(const float4*)(nodes + (size_t)(row0 + r) * D + d0);
    float4 n1 = *(const float4*)(nodes + (size_t)(row0 + r) * D + d0 + 4);
    *(float4*)(&ns[r][d0]) = n0;
    *(float4*)(&ns[r][d0 + 4]) = n1;
    uint4v u;
    u[0] = cvt_pk_f16(n0.x, n0.y); u[1] = cvt_pk_f16(n0.z, n0.w);
    u[2] = cvt_pk_f16(n1.x, n1.y); u[3] = cvt_pk_f16(n1.z, n1.w);
    int g = l16 ^ (r & 7);
    *(uint4v*)(&ah[r * 256 + g * 8]) = u;
    float4 a0 = *(const float4*)(agg + (size_t)(row0 + r) * D + d0);
    float4 a1 = *(const float4*)(agg + (size_t)(row0 + r) * D + d0 + 4);
    u[0] = cvt_pk_f16(a0.x, a0.y); u[1] = cvt_pk_f16(a0.z, a0.w);
    u[2] = cvt_pk_f16(a1.x, a1.y); u[3] = cvt_pk_f16(a1.z, a1.w);
    g = (16 + l16) ^ (r & 7);
    *(uint4v*)(&ah[r * 256 + g * 8]) = u;
    if (tid < 16) msk[tid] = node_mask[row0 + tid];
  }
  __syncthreads();

  const int w = tid >> 6, l = tid & 63;
  const int lg = l >> 4, l15 = l & 15;

  // GEMM1: 16 x 256, K=256
  f32x4 acc[4];
#pragma unroll
  for (int nt = 0; nt < 4; ++nt) acc[nt] = (f32x4){0.f, 0.f, 0.f, 0.f};
#pragma unroll
  for (int ks = 0; ks < 8; ++ks) {
    const int g = (ks * 4 + lg) ^ (l15 & 7);
    f16x8 a = *(const f16x8*)(&ah[l15 * 256 + g * 8]);
#pragma unroll
    for (int nt = 0; nt < 4; ++nt) {
      const int tile = ks * 16 + w * 4 + nt;
      f16x8 bf = *(const f16x8*)(w3f + (size_t)(tile * 64 + l) * 8);
      acc[nt] = __builtin_amdgcn_mfma_f32_16x16x32_f16(a, bf, acc[nt], 0, 0, 0);
    }
  }
  // u = relu(acc + ub1) -> uh (swizzled scalar stores)
#pragma unroll
  for (int nt = 0; nt < 4; ++nt) {
    const int col = w * 64 + nt * 16 + l15;
    const float bias = ub1[col];
#pragma unroll
    for (int r = 0; r < 4; ++r) {
      const int row = lg * 4 + r;
      const int g = (col >> 3) ^ (row & 7);
      uh[row * 256 + g * 8 + (col & 7)] = to_f16u(fmaxf(acc[nt][r] + bias, 0.f));
    }
  }
  __syncthreads();

  // GEMM2: 16 x 128, K=256
  f32x4 acc2[2];
  acc2[0] = (f32x4){0.f, 0.f, 0.f, 0.f};
  acc2[1] = (f32x4){0.f, 0.f, 0.f, 0.f};
#pragma unroll
  for (int ks = 0; ks < 8; ++ks) {
    const int g = (ks * 4 + lg) ^ (l15 & 7);
    f16x8 a = *(const f16x8*)(&uh[l15 * 256 + g * 8]);
#pragma unroll
    for (int nt = 0; nt < 2; ++nt) {
      const int tile = ks * 8 + w * 2 + nt;
      f16x8 bf = *(const f16x8*)(w4f + (size_t)(tile * 64 + l) * 8);
      acc2[nt] = __builtin_amdgcn_mfma_f32_16x16x32_f16(a, bf, acc2[nt], 0, 0, 0);
    }
  }
#pragma unroll
  for (int nt = 0; nt < 2; ++nt) {
    const int col = w * 32 + nt * 16 + l15;
    const float ub2v = ub2[col];
#pragma unroll
    for (int r = 0; r < 4; ++r) {
      const int row = lg * 4 + r;
      out[(size_t)(row0 + row) * D + col] =
          (ns[row][col] + acc2[nt][r] + ub2v) * msk[row];
    }
  }
}

extern "C" void kernel_launch(void* const* d_in, const int* in_sizes, int n_in,
                              void* d_out, int out_size, void* d_ws, size_t ws_size,
                              hipStream_t stream) {
  (void)in_sizes; (void)n_in; (void)out_size; (void)ws_size;
  const float* nodes     = (const float*)d_in[0];
  const float* node_mask = (const float*)d_in[1];
  const float* ln_g      = (const float*)d_in[2];
  const float* ln_b      = (const float*)d_in[3];
  const float* mw1       = (const float*)d_in[4];
  const float* mb1       = (const float*)d_in[5];
  const float* mw2       = (const float*)d_in[6];
  const float* mb2       = (const float*)d_in[7];
  const float* uw1       = (const float*)d_in[8];
  const float* ub1       = (const float*)d_in[9];
  const float* uw2       = (const float*)d_in[10];
  const float* ub2       = (const float*)d_in[11];
  float* out = (float*)d_out;

  char* ws = (char*)d_ws;
  float*          xi_p = (float*)(ws);                               // 4 MB
  unsigned short* xjh  = (unsigned short*)(ws + ((size_t)4 << 20));  // 2 MB
  float*          agg  = (float*)(ws + ((size_t)6 << 20));           // 2 MB
  unsigned short* bw2  = (unsigned short*)(ws + ((size_t)8 << 20));            // 64 KB
  unsigned short* w1f  = (unsigned short*)(ws + ((size_t)8 << 20) + (64 << 10));   // 128 KB
  unsigned short* w3f  = (unsigned short*)(ws + ((size_t)8 << 20) + (192 << 10));  // 128 KB
  unsigned short* w4f  = (unsigned short*)(ws + ((size_t)8 << 20) + (320 << 10));  // 64 KB

  k_repack<<<48, 512, 0, stream>>>(mw1, uw1, uw2, mw2, w1f, w3f, w4f, bw2);
  k_ln_proj<<<dim3(256, 2), 256, 0, stream>>>(nodes, node_mask, ln_g, ln_b, w1f, xi_p, xjh);
  k_msgs<<<dim3(NN / 4, NB), 1024, 0, stream>>>(xi_p, xjh, bw2, mb1, mb2, node_mask, agg);
  k_upd<<<256, 256, 0, stream>>>(nodes, agg, w3f, ub1, w4f, ub2, node_mask, out);
}

// Round 23
// 57.247 us; speedup vs baseline: 1.3545x; 1.1343x over previous
//
#include <hip/hip_runtime.h>
#include <hip/hip_bf16.h>

#define D 128
#define H 256
#define NB 32
#define NN 128

typedef __attribute__((ext_vector_type(8))) _Float16 f16x8;
typedef __attribute__((ext_vector_type(4))) float f32x4;
typedef __attribute__((ext_vector_type(16))) float f32x16;
typedef __attribute__((ext_vector_type(4))) unsigned int uint4v;

__device__ __forceinline__ unsigned short to_f16u(float f) {
  _Float16 h = (_Float16)f;
  return __builtin_bit_cast(unsigned short, h);
}

// packed f32x2 -> f16x2: v_cvt_pkrtz_f16_f32 (verified R17)
__device__ __forceinline__ unsigned cvt_pk_f16(float lo, float hi) {
  unsigned d;
  asm("v_cvt_pkrtz_f16_f32 %0, %1, %2" : "=v"(d) : "v"(lo), "v"(hi));
  return d;
}

// packed f16 add (verified R17); v_pk_add_bf16 does NOT exist (R10)
__device__ __forceinline__ unsigned pk_add_f16(unsigned a, unsigned b) {
  unsigned d;
  asm("v_pk_add_f16 %0, %1, %2" : "=v"(d) : "v"(a), "v"(b));
  return d;
}

// packed relu: signed-i16 max with 0 (verified R7-R17)
__device__ __forceinline__ unsigned pk_relu(unsigned x) {
  unsigned d;
  asm("v_pk_max_i16 %0, %1, %2" : "=v"(d) : "v"(x), "v"(0u));
  return d;
}

// ---------------- Kernel 0: repack all weights to f16 MFMA B-fragment order ----
__global__ __launch_bounds__(512) void k_repack(
    const float* __restrict__ mw1, const float* __restrict__ uw1,
    const float* __restrict__ uw2, const float* __restrict__ mw2,
    unsigned short* __restrict__ w1f, unsigned short* __restrict__ w3f,
    unsigned short* __restrict__ w4f, unsigned short* __restrict__ bw2) {
  const int gt = blockIdx.x * 512 + threadIdx.x;
  const int tile = gt >> 6, l = gt & 63;
  const int lg = l >> 4, l15 = l & 15;
  if (tile < 128) {
    const int ks = tile >> 5, ntg = tile & 31;
#pragma unroll
    for (int e = 0; e < 8; ++e) {
      int k = ks * 32 + lg * 8 + e;
      int col = ntg * 16 + l15;
      float v = (col < 256) ? mw1[k * 256 + col] : mw1[(128 + k) * 256 + (col - 256)];
      w1f[(size_t)(tile * 64 + l) * 8 + e] = to_f16u(v);
    }
  } else if (tile < 256) {
    const int t = tile - 128, ks = t >> 4, ntg = t & 15;
#pragma unroll
    for (int e = 0; e < 8; ++e) {
      int k = ks * 32 + lg * 8 + e;
      w3f[(size_t)(t * 64 + l) * 8 + e] = to_f16u(uw1[k * 256 + ntg * 16 + l15]);
    }
  } else if (tile < 320) {
    const int t = tile - 256, ks = t >> 3, ntg = t & 7;
#pragma unroll
    for (int e = 0; e < 8; ++e) {
      int k = ks * 32 + lg * 8 + e;
      w4f[(size_t)(t * 64 + l) * 8 + e] = to_f16u(uw2[k * 128 + ntg * 16 + l15]);
    }
  } else {
    const int t = tile - 320;            // 0..63: st = t>>2, ntile = t&3
    const int st = t >> 2, ntile = t & 3;
    const int lh = l >> 5, l31 = l & 31;
#pragma unroll
    for (int e = 0; e < 8; ++e) {
      int k = st * 16 + lh * 8 + e;
      bw2[(size_t)(t * 64 + l) * 8 + e] = to_f16u(mw2[k * 128 + ntile * 32 + l31]);
    }
  }
}

// ---------------- Kernel 1: LN*mask -> f16 + projection GEMM via MFMA (R18) ----
__global__ __launch_bounds__(256) void k_ln_proj(
    const float* __restrict__ nodes, const float* __restrict__ node_mask,
    const float* __restrict__ ln_g, const float* __restrict__ ln_b,
    const unsigned short* __restrict__ w1f,
    float* __restrict__ xi_p, unsigned short* __restrict__ xjh) {
  const int row0 = blockIdx.x * 16;
  const int half = blockIdx.y;
  const int tid = threadIdx.x;
  __shared__ unsigned short xh[16 * 128];   // f16, 16B-group swizzled

  {
    const int r = tid >> 4, l16 = tid & 15, d0 = l16 * 8;
    float4 v0 = *(const float4*)(nodes + (size_t)(row0 + r) * D + d0);
    float4 v1 = *(const float4*)(nodes + (size_t)(row0 + r) * D + d0 + 4);
    float s1 = v0.x + v0.y + v0.z + v0.w + v1.x + v1.y + v1.z + v1.w;
    float s2 = v0.x * v0.x + v0.y * v0.y + v0.z * v0.z + v0.w * v0.w +
               v1.x * v1.x + v1.y * v1.y + v1.z * v1.z + v1.w * v1.w;
#pragma unroll
    for (int off = 1; off < 16; off <<= 1) {
      s1 += __shfl_xor(s1, off);
      s2 += __shfl_xor(s2, off);
    }
    float mu = s1 * (1.0f / 128.0f);
    float var = s2 * (1.0f / 128.0f) - mu * mu;
    float rsig = rsqrtf(var + 1e-5f);
    float m = node_mask[row0 + r];
    float4 g0 = *(const float4*)(ln_g + d0), g1 = *(const float4*)(ln_g + d0 + 4);
    float4 b0 = *(const float4*)(ln_b + d0), b1 = *(const float4*)(ln_b + d0 + 4);
    float x0 = ((v0.x - mu) * rsig * g0.x + b0.x) * m;
    float x1 = ((v0.y - mu) * rsig * g0.y + b0.y) * m;
    float x2 = ((v0.z - mu) * rsig * g0.z + b0.z) * m;
    float x3 = ((v0.w - mu) * rsig * g0.w + b0.w) * m;
    float x4 = ((v1.x - mu) * rsig * g1.x + b1.x) * m;
    float x5 = ((v1.y - mu) * rsig * g1.y + b1.y) * m;
    float x6 = ((v1.z - mu) * rsig * g1.z + b1.z) * m;
    float x7 = ((v1.w - mu) * rsig * g1.w + b1.w) * m;
    uint4v u;
    u[0] = cvt_pk_f16(x0, x1); u[1] = cvt_pk_f16(x2, x3);
    u[2] = cvt_pk_f16(x4, x5); u[3] = cvt_pk_f16(x6, x7);
    const int g = l16 ^ (r & 7);          // swizzled 16B-group index
    *(uint4v*)(&xh[r * 128 + g * 8]) = u;
  }
  __syncthreads();

  const int w = tid >> 6, l = tid & 63;
  const int lg = l >> 4, l15 = l & 15;
  f32x4 acc[4];
#pragma unroll
  for (int nt = 0; nt < 4; ++nt) acc[nt] = (f32x4){0.f, 0.f, 0.f, 0.f};

#pragma unroll
  for (int ks = 0; ks < 4; ++ks) {
    const int g = (ks * 4 + lg) ^ (l15 & 7);
    f16x8 a = *(const f16x8*)(&xh[l15 * 128 + g * 8]);
#pragma unroll
    for (int nt = 0; nt < 4; ++nt) {
      const int tile = ks * 32 + half * 16 + w * 4 + nt;
      f16x8 bf = *(const f16x8*)(w1f + (size_t)(tile * 64 + l) * 8);
      acc[nt] = __builtin_amdgcn_mfma_f32_16x16x32_f16(a, bf, acc[nt], 0, 0, 0);
    }
  }

  if (half == 0) {
#pragma unroll
    for (int nt = 0; nt < 4; ++nt)
#pragma unroll
      for (int r = 0; r < 4; ++r)
        xi_p[(size_t)(row0 + lg * 4 + r) * H + w * 64 + nt * 16 + l15] = acc[nt][r];
  } else {
#pragma unroll
    for (int nt = 0; nt < 4; ++nt)
#pragma unroll
      for (int r = 0; r < 4; ++r)
        xjh[(size_t)(row0 + lg * 4 + r) * H + w * 64 + nt * 16 + l15] = to_f16u(acc[nt][r]);
  }
}

// ---------------- Kernel 2: msgs GEMM, persistent blocks (R23) -----------------
// R23 = R22 inner loop, but grid = 256 (1 block/CU, zero tail). Block blk:
// b = blk>>3, iquad0 = (blk&7)*4; loops over 4 items (i0 = iquad0*4 + t*4...
// i0 = ((blk&7)*4 + t) * 4). bw2s + xjs + mask/mb2 staged ONCE per block
// (R22 re-staged 128KB 4x per CU + paid 3 inter-block drain gaps at 1
// block/CU residency -> occupancy read 37% not 50%). Per item only cs2 (2KB)
// re-staged. Inner loop identical to R22. Spill tripwire: WRITE ~4MB.
__global__ __launch_bounds__(1024, 4) void k_msgs(
    const float* __restrict__ xi_p, const unsigned short* __restrict__ xjh,
    const unsigned short* __restrict__ bw2g, const float* __restrict__ mb1,
    const float* __restrict__ mb2, const float* __restrict__ node_mask,
    float* __restrict__ agg) {
  const int blk = blockIdx.x;
  const int b = blk >> 3;
  const int iq0 = (blk & 7) * 4;         // first i-quad of this block
  const int tid = threadIdx.x;           // 0..1023
  const int w = tid >> 6, l = tid & 63;  // 16 waves
  const int ipair = w >> 3;              // 0..1
  const int jslab = (w & 7) >> 1;        // 0..3
  const int nh = w & 1;                  // 0..1
  const int jbase = jslab * 32;
  const int l31 = l & 31, lh = l >> 5;

  __shared__ unsigned short bw2s[32768]; // 64 KB B fragments
  __shared__ unsigned short xjs[32768];  // 64 KB xjh fragments (4096 x 16B)
  __shared__ unsigned cs2[4][128];       // f16-pair (xi_p + mb1), per i
  __shared__ float mb2s[128], maskS[128];
  __shared__ float waveAgg[16][2][64];

  {
    const uint4v* src = (const uint4v*)bw2g;
    uint4v* dst = (uint4v*)bw2s;
#pragma unroll
    for (int c = 0; c < 4; ++c) dst[c * 1024 + tid] = src[c * 1024 + tid];
  }
  {
    // Stage xjh[b] (128 j x 256 k f16) into fragment-tile order (once per blk)
    const int jj = tid & 127;
    const int qq = tid >> 7;             // 0..7 -> chunks qq*4 .. qq*4+3
    const int js = jj >> 5, j31 = jj & 31;
    const unsigned short* grow = xjh + (size_t)(b * NN + jj) * H;
    uint4v* dst = (uint4v*)xjs;
#pragma unroll
    for (int r = 0; r < 4; ++r) {
      const int c = qq * 4 + r;          // 0..31
      const int st = c >> 1, lhh = c & 1;
      dst[((js * 16 + st) * 2 + lhh) * 32 + j31] =
          *(const uint4v*)(grow + c * 8);
    }
  }
  if (tid < 128) { mb2s[tid] = mb2[tid]; maskS[tid] = node_mask[b * NN + tid]; }

  const uint4v* bfrag = (const uint4v*)bw2s;
  const uint4v* xfrag = (const uint4v*)xjs;

  for (int t = 0; t < 4; ++t) {
    const int i0 = (iq0 + t) * 4;
    __syncthreads();                     // prior item done with cs2/waveAgg
    if (tid < 512) {
      int ii = tid >> 7, p = tid & 127;  // 4 i's x 128 pairs
      float2 xi2 = *(const float2*)(xi_p + (size_t)(b * NN + i0 + ii) * H + 2 * p);
      float2 mbv = *(const float2*)(mb1 + 2 * p);
      cs2[ii][p] = cvt_pk_f16(xi2.x + mbv.x, xi2.y + mbv.y);
    }
    __syncthreads();

    f32x16 acc[2][2];                    // [i-of-pair][ntile]
#pragma unroll
    for (int ii = 0; ii < 2; ++ii)
#pragma unroll
      for (int nt = 0; nt < 2; ++nt)
#pragma unroll
        for (int r = 0; r < 16; ++r) acc[ii][nt][r] = 0.f;

#pragma unroll
    for (int st = 0; st < 16; ++st) {
      const int kb = st * 16 + lh * 8;   // f16-elem k offset
      uint4v xu = xfrag[((jslab * 16 + st) * 2 + lh) * 32 + l31];
      uint4v cc0 = *(const uint4v*)(&cs2[ipair * 2 + 0][kb >> 1]);
      uint4v cc1 = *(const uint4v*)(&cs2[ipair * 2 + 1][kb >> 1]);
      uint4v a0, a1;
#pragma unroll
      for (int p = 0; p < 4; ++p) {
        a0[p] = pk_relu(pk_add_f16(xu[p], cc0[p]));
        a1[p] = pk_relu(pk_add_f16(xu[p], cc1[p]));
      }
      f16x8 af0 = __builtin_bit_cast(f16x8, a0);
      f16x8 af1 = __builtin_bit_cast(f16x8, a1);
#pragma unroll
      for (int nt = 0; nt < 2; ++nt) {
        f16x8 bf = __builtin_bit_cast(f16x8, bfrag[(st * 4 + nh * 2 + nt) * 64 + l]);
        acc[0][nt] = __builtin_amdgcn_mfma_f32_32x32x16_f16(af0, bf, acc[0][nt], 0, 0, 0);
        acc[1][nt] = __builtin_amdgcn_mfma_f32_32x32x16_f16(af1, bf, acc[1][nt], 0, 0, 0);
      }
    }

    // Epilogue: relu(acc+mb2)*mask_j, column-sum over the tile's 32 j rows.
#pragma unroll
    for (int ii = 0; ii < 2; ++ii)
#pragma unroll
      for (int nt = 0; nt < 2; ++nt) {
        const float bias = mb2s[nh * 64 + nt * 32 + l31];
        float s = 0.f;
#pragma unroll
        for (int reg = 0; reg < 16; ++reg) {
          const int j = jbase + 4 * lh + (reg & 3) + 8 * (reg >> 2);
          s = fmaf(fmaxf(acc[ii][nt][reg] + bias, 0.f), maskS[j], s);
        }
        s += __shfl_xor(s, 32);
        if (l < 32) waveAgg[w][ii][nt * 32 + l31] = s;
      }
    __syncthreads();
    if (tid < 512) {
      const int ii4 = tid >> 7, col = tid & 127;  // 4 i's x 128 cols
      const int ipq = ii4 >> 1, iwi = ii4 & 1;
      const int nh2 = col >> 6, c6 = col & 63;
      agg[(size_t)(b * NN + i0 + ii4) * D + col] =
          waveAgg[ipq * 8 + 0 + nh2][iwi][c6] + waveAgg[ipq * 8 + 2 + nh2][iwi][c6] +
          waveAgg[ipq * 8 + 4 + nh2][iwi][c6] + waveAgg[ipq * 8 + 6 + nh2][iwi][c6];
    }
  }
}

// ---------------- Kernel 3: update MLP via MFMA + residual + mask (R18) --------
__global__ __launch_bounds__(256) void k_upd(
    const float* __restrict__ nodes, const float* __restrict__ agg,
    const unsigned short* __restrict__ w3f, const float* __restrict__ ub1,
    const unsigned short* __restrict__ w4f, const float* __restrict__ ub2,
    const float* __restrict__ node_mask, float* __restrict__ out) {
  const int row0 = blockIdx.x * 16;
  const int tid = threadIdx.x;
  __shared__ unsigned short ah[16 * 256];  // f16 [16][32 groups], swizzled
  __shared__ unsigned short uh[16 * 256];  // f16 u, swizzled
  __shared__ float ns[16][128];
  __shared__ float msk[16];

  {
    const int r = tid >> 4, l16 = tid & 15, d0 = l16 * 8;
    float4 n0 = *(const float4*)(nodes + (size_t)(row0 + r) * D + d0);
    float4 n1 = *(const float4*)(nodes + (size_t)(row0 + r) * D + d0 + 4);
    *(float4*)(&ns[r][d0]) = n0;
    *(float4*)(&ns[r][d0 + 4]) = n1;
    uint4v u;
    u[0] = cvt_pk_f16(n0.x, n0.y); u[1] = cvt_pk_f16(n0.z, n0.w);
    u[2] = cvt_pk_f16(n1.x, n1.y); u[3] = cvt_pk_f16(n1.z, n1.w);
    int g = l16 ^ (r & 7);
    *(uint4v*)(&ah[r * 256 + g * 8]) = u;
    float4 a0 = *(const float4*)(agg + (size_t)(row0 + r) * D + d0);
    float4 a1 = *(const float4*)(agg + (size_t)(row0 + r) * D + d0 + 4);
    u[0] = cvt_pk_f16(a0.x, a0.y); u[1] = cvt_pk_f16(a0.z, a0.w);
    u[2] = cvt_pk_f16(a1.x, a1.y); u[3] = cvt_pk_f16(a1.z, a1.w);
    g = (16 + l16) ^ (r & 7);
    *(uint4v*)(&ah[r * 256 + g * 8]) = u;
    if (tid < 16) msk[tid] = node_mask[row0 + tid];
  }
  __syncthreads();

  const int w = tid >> 6, l = tid & 63;
  const int lg = l >> 4, l15 = l & 15;

  // GEMM1: 16 x 256, K=256
  f32x4 acc[4];
#pragma unroll
  for (int nt = 0; nt < 4; ++nt) acc[nt] = (f32x4){0.f, 0.f, 0.f, 0.f};
#pragma unroll
  for (int ks = 0; ks < 8; ++ks) {
    const int g = (ks * 4 + lg) ^ (l15 & 7);
    f16x8 a = *(const f16x8*)(&ah[l15 * 256 + g * 8]);
#pragma unroll
    for (int nt = 0; nt < 4; ++nt) {
      const int tile = ks * 16 + w * 4 + nt;
      f16x8 bf = *(const f16x8*)(w3f + (size_t)(tile * 64 + l) * 8);
      acc[nt] = __builtin_amdgcn_mfma_f32_16x16x32_f16(a, bf, acc[nt], 0, 0, 0);
    }
  }
  // u = relu(acc + ub1) -> uh (swizzled scalar stores)
#pragma unroll
  for (int nt = 0; nt < 4; ++nt) {
    const int col = w * 64 + nt * 16 + l15;
    const float bias = ub1[col];
#pragma unroll
    for (int r = 0; r < 4; ++r) {
      const int row = lg * 4 + r;
      const int g = (col >> 3) ^ (row & 7);
      uh[row * 256 + g * 8 + (col & 7)] = to_f16u(fmaxf(acc[nt][r] + bias, 0.f));
    }
  }
  __syncthreads();

  // GEMM2: 16 x 128, K=256
  f32x4 acc2[2];
  acc2[0] = (f32x4){0.f, 0.f, 0.f, 0.f};
  acc2[1] = (f32x4){0.f, 0.f, 0.f, 0.f};
#pragma unroll
  for (int ks = 0; ks < 8; ++ks) {
    const int g = (ks * 4 + lg) ^ (l15 & 7);
    f16x8 a = *(const f16x8*)(&uh[l15 * 256 + g * 8]);
#pragma unroll
    for (int nt = 0; nt < 2; ++nt) {
      const int tile = ks * 8 + w * 2 + nt;
      f16x8 bf = *(const f16x8*)(w4f + (size_t)(tile * 64 + l) * 8);
      acc2[nt] = __builtin_amdgcn_mfma_f32_16x16x32_f16(a, bf, acc2[nt], 0, 0, 0);
    }
  }
#pragma unroll
  for (int nt = 0; nt < 2; ++nt) {
    const int col = w * 32 + nt * 16 + l15;
    const float ub2v = ub2[col];
#pragma unroll
    for (int r = 0; r < 4; ++r) {
      const int row = lg * 4 + r;
      out[(size_t)(row0 + row) * D + col] =
          (ns[row][col] + acc2[nt][r] + ub2v) * msk[row];
    }
  }
}

extern "C" void kernel_launch(void* const* d_in, const int* in_sizes, int n_in,
                              void* d_out, int out_size, void* d_ws, size_t ws_size,
                              hipStream_t stream) {
  (void)in_sizes; (void)n_in; (void)out_size; (void)ws_size;
  const float* nodes     = (const float*)d_in[0];
  const float* node_mask = (const float*)d_in[1];
  const float* ln_g      = (const float*)d_in[2];
  const float* ln_b      = (const float*)d_in[3];
  const float* mw1       = (const float*)d_in[4];
  const float* mb1       = (const float*)d_in[5];
  const float* mw2       = (const float*)d_in[6];
  const float* mb2       = (const float*)d_in[7];
  const float* uw1       = (const float*)d_in[8];
  const float* ub1       = (const float*)d_in[9];
  const float* uw2       = (const float*)d_in[10];
  const float* ub2       = (const float*)d_in[11];
  float* out = (float*)d_out;

  char* ws = (char*)d_ws;
  float*          xi_p = (float*)(ws);                               // 4 MB
  unsigned short* xjh  = (unsigned short*)(ws + ((size_t)4 << 20));  // 2 MB
  float*          agg  = (float*)(ws + ((size_t)6 << 20));           // 2 MB
  unsigned short* bw2  = (unsigned short*)(ws + ((size_t)8 << 20));            // 64 KB
  unsigned short* w1f  = (unsigned short*)(ws + ((size_t)8 << 20) + (64 << 10));   // 128 KB
  unsigned short* w3f  = (unsigned short*)(ws + ((size_t)8 << 20) + (192 << 10));  // 128 KB
  unsigned short* w4f  = (unsigned short*)(ws + ((size_t)8 << 20) + (320 << 10));  // 64 KB

  k_repack<<<48, 512, 0, stream>>>(mw1, uw1, uw2, mw2, w1f, w3f, w4f, bw2);
  k_ln_proj<<<dim3(256, 2), 256, 0, stream>>>(nodes, node_mask, ln_g, ln_b, w1f, xi_p, xjh);
  k_msgs<<<256, 1024, 0, stream>>>(xi_p, xjh, bw2, mb1, mb2, node_mask, agg);
  k_upd<<<256, 256, 0, stream>>>(nodes, agg, w3f, ub1, w4f, ub2, node_mask, out);
}

// Round 24
// 54.700 us; speedup vs baseline: 1.4176x; 1.0466x over previous
//
#include <hip/hip_runtime.h>
#include <hip/hip_bf16.h>

#define D 128
#define H 256
#define NB 32
#define NN 128

typedef __attribute__((ext_vector_type(8))) _Float16 f16x8;
typedef __attribute__((ext_vector_type(4))) float f32x4;
typedef __attribute__((ext_vector_type(16))) float f32x16;
typedef __attribute__((ext_vector_type(4))) unsigned int uint4v;

__device__ __forceinline__ unsigned short to_f16u(float f) {
  _Float16 h = (_Float16)f;
  return __builtin_bit_cast(unsigned short, h);
}

// packed f32x2 -> f16x2: v_cvt_pkrtz_f16_f32 (verified R17)
__device__ __forceinline__ unsigned cvt_pk_f16(float lo, float hi) {
  unsigned d;
  asm("v_cvt_pkrtz_f16_f32 %0, %1, %2" : "=v"(d) : "v"(lo), "v"(hi));
  return d;
}

// packed f16 add (verified R17); v_pk_add_bf16 does NOT exist (R10)
__device__ __forceinline__ unsigned pk_add_f16(unsigned a, unsigned b) {
  unsigned d;
  asm("v_pk_add_f16 %0, %1, %2" : "=v"(d) : "v"(a), "v"(b));
  return d;
}

// packed relu: signed-i16 max with 0 (verified R7-R17)
__device__ __forceinline__ unsigned pk_relu(unsigned x) {
  unsigned d;
  asm("v_pk_max_i16 %0, %1, %2" : "=v"(d) : "v"(x), "v"(0u));
  return d;
}

// ---------------- Kernel 0: repack all weights to f16 MFMA B-fragment order ----
__global__ __launch_bounds__(512) void k_repack(
    const float* __restrict__ mw1, const float* __restrict__ uw1,
    const float* __restrict__ uw2, const float* __restrict__ mw2,
    unsigned short* __restrict__ w1f, unsigned short* __restrict__ w3f,
    unsigned short* __restrict__ w4f, unsigned short* __restrict__ bw2) {
  const int gt = blockIdx.x * 512 + threadIdx.x;
  const int tile = gt >> 6, l = gt & 63;
  const int lg = l >> 4, l15 = l & 15;
  if (tile < 128) {
    const int ks = tile >> 5, ntg = tile & 31;
#pragma unroll
    for (int e = 0; e < 8; ++e) {
      int k = ks * 32 + lg * 8 + e;
      int col = ntg * 16 + l15;
      float v = (col < 256) ? mw1[k * 256 + col] : mw1[(128 + k) * 256 + (col - 256)];
      w1f[(size_t)(tile * 64 + l) * 8 + e] = to_f16u(v);
    }
  } else if (tile < 256) {
    const int t = tile - 128, ks = t >> 4, ntg = t & 15;
#pragma unroll
    for (int e = 0; e < 8; ++e) {
      int k = ks * 32 + lg * 8 + e;
      w3f[(size_t)(t * 64 + l) * 8 + e] = to_f16u(uw1[k * 256 + ntg * 16 + l15]);
    }
  } else if (tile < 320) {
    const int t = tile - 256, ks = t >> 3, ntg = t & 7;
#pragma unroll
    for (int e = 0; e < 8; ++e) {
      int k = ks * 32 + lg * 8 + e;
      w4f[(size_t)(t * 64 + l) * 8 + e] = to_f16u(uw2[k * 128 + ntg * 16 + l15]);
    }
  } else {
    const int t = tile - 320;            // 0..63: st = t>>2, ntile = t&3
    const int st = t >> 2, ntile = t & 3;
    const int lh = l >> 5, l31 = l & 31;
#pragma unroll
    for (int e = 0; e < 8; ++e) {
      int k = st * 16 + lh * 8 + e;
      bw2[(size_t)(t * 64 + l) * 8 + e] = to_f16u(mw2[k * 128 + ntile * 32 + l31]);
    }
  }
}

// ---------------- Kernel 1: LN*mask -> f16 + projection GEMM via MFMA (R18) ----
__global__ __launch_bounds__(256) void k_ln_proj(
    const float* __restrict__ nodes, const float* __restrict__ node_mask,
    const float* __restrict__ ln_g, const float* __restrict__ ln_b,
    const unsigned short* __restrict__ w1f,
    float* __restrict__ xi_p, unsigned short* __restrict__ xjh) {
  const int row0 = blockIdx.x * 16;
  const int half = blockIdx.y;
  const int tid = threadIdx.x;
  __shared__ unsigned short xh[16 * 128];   // f16, 16B-group swizzled

  {
    const int r = tid >> 4, l16 = tid & 15, d0 = l16 * 8;
    float4 v0 = *(const float4*)(nodes + (size_t)(row0 + r) * D + d0);
    float4 v1 = *(const float4*)(nodes + (size_t)(row0 + r) * D + d0 + 4);
    float s1 = v0.x + v0.y + v0.z + v0.w + v1.x + v1.y + v1.z + v1.w;
    float s2 = v0.x * v0.x + v0.y * v0.y + v0.z * v0.z + v0.w * v0.w +
               v1.x * v1.x + v1.y * v1.y + v1.z * v1.z + v1.w * v1.w;
#pragma unroll
    for (int off = 1; off < 16; off <<= 1) {
      s1 += __shfl_xor(s1, off);
      s2 += __shfl_xor(s2, off);
    }
    float mu = s1 * (1.0f / 128.0f);
    float var = s2 * (1.0f / 128.0f) - mu * mu;
    float rsig = rsqrtf(var + 1e-5f);
    float m = node_mask[row0 + r];
    float4 g0 = *(const float4*)(ln_g + d0), g1 = *(const float4*)(ln_g + d0 + 4);
    float4 b0 = *(const float4*)(ln_b + d0), b1 = *(const float4*)(ln_b + d0 + 4);
    float x0 = ((v0.x - mu) * rsig * g0.x + b0.x) * m;
    float x1 = ((v0.y - mu) * rsig * g0.y + b0.y) * m;
    float x2 = ((v0.z - mu) * rsig * g0.z + b0.z) * m;
    float x3 = ((v0.w - mu) * rsig * g0.w + b0.w) * m;
    float x4 = ((v1.x - mu) * rsig * g1.x + b1.x) * m;
    float x5 = ((v1.y - mu) * rsig * g1.y + b1.y) * m;
    float x6 = ((v1.z - mu) * rsig * g1.z + b1.z) * m;
    float x7 = ((v1.w - mu) * rsig * g1.w + b1.w) * m;
    uint4v u;
    u[0] = cvt_pk_f16(x0, x1); u[1] = cvt_pk_f16(x2, x3);
    u[2] = cvt_pk_f16(x4, x5); u[3] = cvt_pk_f16(x6, x7);
    const int g = l16 ^ (r & 7);          // swizzled 16B-group index
    *(uint4v*)(&xh[r * 128 + g * 8]) = u;
  }
  __syncthreads();

  const int w = tid >> 6, l = tid & 63;
  const int lg = l >> 4, l15 = l & 15;
  f32x4 acc[4];
#pragma unroll
  for (int nt = 0; nt < 4; ++nt) acc[nt] = (f32x4){0.f, 0.f, 0.f, 0.f};

#pragma unroll
  for (int ks = 0; ks < 4; ++ks) {
    const int g = (ks * 4 + lg) ^ (l15 & 7);
    f16x8 a = *(const f16x8*)(&xh[l15 * 128 + g * 8]);
#pragma unroll
    for (int nt = 0; nt < 4; ++nt) {
      const int tile = ks * 32 + half * 16 + w * 4 + nt;
      f16x8 bf = *(const f16x8*)(w1f + (size_t)(tile * 64 + l) * 8);
      acc[nt] = __builtin_amdgcn_mfma_f32_16x16x32_f16(a, bf, acc[nt], 0, 0, 0);
    }
  }

  if (half == 0) {
#pragma unroll
    for (int nt = 0; nt < 4; ++nt)
#pragma unroll
      for (int r = 0; r < 4; ++r)
        xi_p[(size_t)(row0 + lg * 4 + r) * H + w * 64 + nt * 16 + l15] = acc[nt][r];
  } else {
#pragma unroll
    for (int nt = 0; nt < 4; ++nt)
#pragma unroll
      for (int r = 0; r < 4; ++r)
        xjh[(size_t)(row0 + lg * 4 + r) * H + w * 64 + nt * 16 + l15] = to_f16u(acc[nt][r]);
  }
}

// ---------------- Kernel 2: msgs GEMM (R23 persistent) + FUSED update MLP ------
// R24: each block owns rows (b, i16..i16+16) = exactly one k_upd block's work.
// agg kept in LDS (aggL) -> no global round-trip; after the 4-item loop the
// dead xjs region is overlaid with ah/uh/ns and the update MLP runs in-block
// (GEMM1: 16 waves x 16-col tiles; GEMM2: 8 waves). k_upd launch deleted.
// LDS pool 147KB -> 1 block/CU, 16 waves = 4/SIMD (same residency as R23).
// Inner msgs loop identical to R23 (41.7us). Spill tripwire: WRITE ~4MB.
__global__ __launch_bounds__(1024, 4) void k_msgs(
    const float* __restrict__ xi_p, const unsigned short* __restrict__ xjh,
    const unsigned short* __restrict__ bw2g, const float* __restrict__ mb1,
    const float* __restrict__ mb2, const float* __restrict__ node_mask,
    const float* __restrict__ nodes, const unsigned short* __restrict__ w3f,
    const float* __restrict__ ub1, const unsigned short* __restrict__ w4f,
    const float* __restrict__ ub2, float* __restrict__ out) {
  const int blk = blockIdx.x;
  const int b = blk >> 3;
  const int iq0 = (blk & 7) * 4;         // first i-quad of this block
  const int i16 = (blk & 7) * 16;        // first row of this block's 16
  const int tid = threadIdx.x;           // 0..1023
  const int w = tid >> 6, l = tid & 63;  // 16 waves
  const int ipair = w >> 3;              // 0..1
  const int jslab = (w & 7) >> 1;        // 0..3
  const int nh = w & 1;                  // 0..1
  const int jbase = jslab * 32;
  const int l31 = l & 31, lh = l >> 5;
  const int lg = (l >> 4) & 3, l15 = l & 15;

  __shared__ __align__(16) char smem[150528];  // 147 KB pool
  unsigned short* bw2s = (unsigned short*)smem;            // 64 KB
  unsigned short* xjs  = (unsigned short*)(smem + 65536);  // 64 KB
  unsigned* cs2        = (unsigned*)(smem + 131072);       // 2 KB [4][128]
  float* mb2s          = (float*)(smem + 133120);          // 512 B
  float* maskS         = (float*)(smem + 133632);          // 512 B
  float* waveAgg       = (float*)(smem + 134144);          // 8 KB [16][2][64]
  float* aggL          = (float*)(smem + 142336);          // 8 KB [16][128]
  // k3-phase overlay (xjs dead after main loop):
  unsigned short* ah   = (unsigned short*)(smem + 65536);  // 8 KB [16][256]
  unsigned short* uh   = (unsigned short*)(smem + 73728);  // 8 KB [16][256]
  float* nsf           = (float*)(smem + 81920);           // 8 KB [16][128]
  float* msk           = (float*)(smem + 90112);           // 64 B

  {
    const uint4v* src = (const uint4v*)bw2g;
    uint4v* dst = (uint4v*)bw2s;
#pragma unroll
    for (int c = 0; c < 4; ++c) dst[c * 1024 + tid] = src[c * 1024 + tid];
  }
  {
    // Stage xjh[b] (128 j x 256 k f16) into fragment-tile order (once per blk)
    const int jj = tid & 127;
    const int qq = tid >> 7;             // 0..7 -> chunks qq*4 .. qq*4+3
    const int js = jj >> 5, j31 = jj & 31;
    const unsigned short* grow = xjh + (size_t)(b * NN + jj) * H;
    uint4v* dst = (uint4v*)xjs;
#pragma unroll
    for (int r = 0; r < 4; ++r) {
      const int c = qq * 4 + r;          // 0..31
      const int st = c >> 1, lhh = c & 1;
      dst[((js * 16 + st) * 2 + lhh) * 32 + j31] =
          *(const uint4v*)(grow + c * 8);
    }
  }
  if (tid < 128) { mb2s[tid] = mb2[tid]; maskS[tid] = node_mask[b * NN + tid]; }

  const uint4v* bfrag = (const uint4v*)bw2s;
  const uint4v* xfrag = (const uint4v*)xjs;

  for (int t = 0; t < 4; ++t) {
    const int i0 = (iq0 + t) * 4;
    __syncthreads();                     // prior item done with cs2/waveAgg
    if (tid < 512) {
      int ii = tid >> 7, p = tid & 127;  // 4 i's x 128 pairs
      float2 xi2 = *(const float2*)(xi_p + (size_t)(b * NN + i0 + ii) * H + 2 * p);
      float2 mbv = *(const float2*)(mb1 + 2 * p);
      cs2[ii * 128 + p] = cvt_pk_f16(xi2.x + mbv.x, xi2.y + mbv.y);
    }
    __syncthreads();

    f32x16 acc[2][2];                    // [i-of-pair][ntile]
#pragma unroll
    for (int ii = 0; ii < 2; ++ii)
#pragma unroll
      for (int nt = 0; nt < 2; ++nt)
#pragma unroll
        for (int r = 0; r < 16; ++r) acc[ii][nt][r] = 0.f;

#pragma unroll
    for (int st = 0; st < 16; ++st) {
      const int kb = st * 16 + lh * 8;   // f16-elem k offset
      uint4v xu = xfrag[((jslab * 16 + st) * 2 + lh) * 32 + l31];
      uint4v cc0 = *(const uint4v*)(&cs2[(ipair * 2 + 0) * 128 + (kb >> 1)]);
      uint4v cc1 = *(const uint4v*)(&cs2[(ipair * 2 + 1) * 128 + (kb >> 1)]);
      uint4v a0, a1;
#pragma unroll
      for (int p = 0; p < 4; ++p) {
        a0[p] = pk_relu(pk_add_f16(xu[p], cc0[p]));
        a1[p] = pk_relu(pk_add_f16(xu[p], cc1[p]));
      }
      f16x8 af0 = __builtin_bit_cast(f16x8, a0);
      f16x8 af1 = __builtin_bit_cast(f16x8, a1);
#pragma unroll
      for (int nt = 0; nt < 2; ++nt) {
        f16x8 bf = __builtin_bit_cast(f16x8, bfrag[(st * 4 + nh * 2 + nt) * 64 + l]);
        acc[0][nt] = __builtin_amdgcn_mfma_f32_32x32x16_f16(af0, bf, acc[0][nt], 0, 0, 0);
        acc[1][nt] = __builtin_amdgcn_mfma_f32_32x32x16_f16(af1, bf, acc[1][nt], 0, 0, 0);
      }
    }

    // Epilogue: relu(acc+mb2)*mask_j, column-sum -> aggL (LDS, not global).
#pragma unroll
    for (int ii = 0; ii < 2; ++ii)
#pragma unroll
      for (int nt = 0; nt < 2; ++nt) {
        const float bias = mb2s[nh * 64 + nt * 32 + l31];
        float s = 0.f;
#pragma unroll
        for (int reg = 0; reg < 16; ++reg) {
          const int j = jbase + 4 * lh + (reg & 3) + 8 * (reg >> 2);
          s = fmaf(fmaxf(acc[ii][nt][reg] + bias, 0.f), maskS[j], s);
        }
        s += __shfl_xor(s, 32);
        if (l < 32) waveAgg[((w * 2) + ii) * 64 + nt * 32 + l31] = s;
      }
    __syncthreads();
    if (tid < 512) {
      const int ii4 = tid >> 7, col = tid & 127;  // 4 i's x 128 cols
      const int ipq = ii4 >> 1, iwi = ii4 & 1;
      const int nh2 = col >> 6, c6 = col & 63;
      aggL[(t * 4 + ii4) * 128 + col] =
          waveAgg[((ipq * 8 + 0 + nh2) * 2 + iwi) * 64 + c6] +
          waveAgg[((ipq * 8 + 2 + nh2) * 2 + iwi) * 64 + c6] +
          waveAgg[((ipq * 8 + 4 + nh2) * 2 + iwi) * 64 + c6] +
          waveAgg[((ipq * 8 + 6 + nh2) * 2 + iwi) * 64 + c6];
    }
  }
  __syncthreads();   // aggL complete; xjs dead -> overlay ah/uh/nsf

  // ---------- Fused update MLP for this block's 16 rows ----------
  if (tid < 256) {
    const int r = tid >> 4, l16 = tid & 15, d0 = l16 * 8;
    const size_t grow = (size_t)(b * NN + i16 + r) * D;
    float4 n0 = *(const float4*)(nodes + grow + d0);
    float4 n1 = *(const float4*)(nodes + grow + d0 + 4);
    *(float4*)(&nsf[r * 128 + d0]) = n0;
    *(float4*)(&nsf[r * 128 + d0 + 4]) = n1;
    uint4v u;
    u[0] = cvt_pk_f16(n0.x, n0.y); u[1] = cvt_pk_f16(n0.z, n0.w);
    u[2] = cvt_pk_f16(n1.x, n1.y); u[3] = cvt_pk_f16(n1.z, n1.w);
    int g = l16 ^ (r & 7);
    *(uint4v*)(&ah[r * 256 + g * 8]) = u;
    float4 a0 = *(const float4*)(&aggL[r * 128 + d0]);
    float4 a1 = *(const float4*)(&aggL[r * 128 + d0 + 4]);
    u[0] = cvt_pk_f16(a0.x, a0.y); u[1] = cvt_pk_f16(a0.z, a0.w);
    u[2] = cvt_pk_f16(a1.x, a1.y); u[3] = cvt_pk_f16(a1.z, a1.w);
    g = (16 + l16) ^ (r & 7);
    *(uint4v*)(&ah[r * 256 + g * 8]) = u;
    if (tid < 16) msk[tid] = node_mask[b * NN + i16 + tid];
  }
  __syncthreads();

  // GEMM1: 16x256, K=256; 16 waves, one 16-col tile each.
  {
    f32x4 acc3 = (f32x4){0.f, 0.f, 0.f, 0.f};
#pragma unroll
    for (int ks = 0; ks < 8; ++ks) {
      const int g = (ks * 4 + lg) ^ (l15 & 7);
      f16x8 a = *(const f16x8*)(&ah[l15 * 256 + g * 8]);
      f16x8 bf = *(const f16x8*)(w3f + (size_t)((ks * 16 + w) * 64 + l) * 8);
      acc3 = __builtin_amdgcn_mfma_f32_16x16x32_f16(a, bf, acc3, 0, 0, 0);
    }
    const int col = w * 16 + l15;
    const float bias = ub1[col];
#pragma unroll
    for (int r = 0; r < 4; ++r) {
      const int row = lg * 4 + r;
      const int g2 = (col >> 3) ^ (row & 7);
      uh[row * 256 + g2 * 8 + (col & 7)] = to_f16u(fmaxf(acc3[r] + bias, 0.f));
    }
  }
  __syncthreads();

  // GEMM2: 16x128, K=256; waves 0..7, one 16-col tile each.
  if (w < 8) {
    f32x4 acc4 = (f32x4){0.f, 0.f, 0.f, 0.f};
#pragma unroll
    for (int ks = 0; ks < 8; ++ks) {
      const int g = (ks * 4 + lg) ^ (l15 & 7);
      f16x8 a = *(const f16x8*)(&uh[l15 * 256 + g * 8]);
      f16x8 bf = *(const f16x8*)(w4f + (size_t)((ks * 8 + w) * 64 + l) * 8);
      acc4 = __builtin_amdgcn_mfma_f32_16x16x32_f16(a, bf, acc4, 0, 0, 0);
    }
    const int col = w * 16 + l15;
    const float ub2v = ub2[col];
#pragma unroll
    for (int r = 0; r < 4; ++r) {
      const int row = lg * 4 + r;
      out[(size_t)(b * NN + i16 + row) * D + col] =
          (nsf[row * 128 + col] + acc4[r] + ub2v) * msk[row];
    }
  }
}

extern "C" void kernel_launch(void* const* d_in, const int* in_sizes, int n_in,
                              void* d_out, int out_size, void* d_ws, size_t ws_size,
                              hipStream_t stream) {
  (void)in_sizes; (void)n_in; (void)out_size; (void)ws_size;
  const float* nodes     = (const float*)d_in[0];
  const float* node_mask = (const float*)d_in[1];
  const float* ln_g      = (const float*)d_in[2];
  const float* ln_b      = (const float*)d_in[3];
  const float* mw1       = (const float*)d_in[4];
  const float* mb1       = (const float*)d_in[5];
  const float* mw2       = (const float*)d_in[6];
  const float* mb2       = (const float*)d_in[7];
  const float* uw1       = (const float*)d_in[8];
  const float* ub1       = (const float*)d_in[9];
  const float* uw2       = (const float*)d_in[10];
  const float* ub2       = (const float*)d_in[11];
  float* out = (float*)d_out;

  char* ws = (char*)d_ws;
  float*          xi_p = (float*)(ws);                               // 4 MB
  unsigned short* xjh  = (unsigned short*)(ws + ((size_t)4 << 20));  // 2 MB
  unsigned short* bw2  = (unsigned short*)(ws + ((size_t)6 << 20));            // 64 KB
  unsigned short* w1f  = (unsigned short*)(ws + ((size_t)6 << 20) + (64 << 10));   // 128 KB
  unsigned short* w3f  = (unsigned short*)(ws + ((size_t)6 << 20) + (192 << 10));  // 128 KB
  unsigned short* w4f  = (unsigned short*)(ws + ((size_t)6 << 20) + (320 << 10));  // 64 KB

  k_repack<<<48, 512, 0, stream>>>(mw1, uw1, uw2, mw2, w1f, w3f, w4f, bw2);
  k_ln_proj<<<dim3(256, 2), 256, 0, stream>>>(nodes, node_mask, ln_g, ln_b, w1f, xi_p, xjh);
  k_msgs<<<256, 1024, 0, stream>>>(xi_p, xjh, bw2, mb1, mb2, node_mask,
                                   nodes, w3f, ub1, w4f, ub2, out);
}

// Round 25
// 52.358 us; speedup vs baseline: 1.4810x; 1.0447x over previous
//
#include <hip/hip_runtime.h>
#include <hip/hip_bf16.h>

#define D 128
#define H 256
#define NB 32
#define NN 128

typedef __attribute__((ext_vector_type(8))) _Float16 f16x8;
typedef __attribute__((ext_vector_type(4))) float f32x4;
typedef __attribute__((ext_vector_type(16))) float f32x16;
typedef __attribute__((ext_vector_type(2))) unsigned int uint2v;
typedef __attribute__((ext_vector_type(4))) unsigned int uint4v;

__device__ __forceinline__ unsigned short to_f16u(float f) {
  _Float16 h = (_Float16)f;
  return __builtin_bit_cast(unsigned short, h);
}

// packed f32x2 -> f16x2: v_cvt_pkrtz_f16_f32 (verified R17)
__device__ __forceinline__ unsigned cvt_pk_f16(float lo, float hi) {
  unsigned d;
  asm("v_cvt_pkrtz_f16_f32 %0, %1, %2" : "=v"(d) : "v"(lo), "v"(hi));
  return d;
}

// packed f16 add (verified R17); v_pk_add_bf16 does NOT exist (R10)
__device__ __forceinline__ unsigned pk_add_f16(unsigned a, unsigned b) {
  unsigned d;
  asm("v_pk_add_f16 %0, %1, %2" : "=v"(d) : "v"(a), "v"(b));
  return d;
}

// packed relu: signed-i16 max with 0 (verified R7-R17)
__device__ __forceinline__ unsigned pk_relu(unsigned x) {
  unsigned d;
  asm("v_pk_max_i16 %0, %1, %2" : "=v"(d) : "v"(x), "v"(0u));
  return d;
}

// ---------------- Kernel 0: repack all weights to f16 MFMA B-fragment order ----
__global__ __launch_bounds__(512) void k_repack(
    const float* __restrict__ mw1, const float* __restrict__ uw1,
    const float* __restrict__ uw2, const float* __restrict__ mw2,
    unsigned short* __restrict__ w1f, unsigned short* __restrict__ w3f,
    unsigned short* __restrict__ w4f, unsigned short* __restrict__ bw2) {
  const int gt = blockIdx.x * 512 + threadIdx.x;
  const int tile = gt >> 6, l = gt & 63;
  const int lg = l >> 4, l15 = l & 15;
  if (tile < 128) {
    const int ks = tile >> 5, ntg = tile & 31;
#pragma unroll
    for (int e = 0; e < 8; ++e) {
      int k = ks * 32 + lg * 8 + e;
      int col = ntg * 16 + l15;
      float v = (col < 256) ? mw1[k * 256 + col] : mw1[(128 + k) * 256 + (col - 256)];
      w1f[(size_t)(tile * 64 + l) * 8 + e] = to_f16u(v);
    }
  } else if (tile < 256) {
    const int t = tile - 128, ks = t >> 4, ntg = t & 15;
#pragma unroll
    for (int e = 0; e < 8; ++e) {
      int k = ks * 32 + lg * 8 + e;
      w3f[(size_t)(t * 64 + l) * 8 + e] = to_f16u(uw1[k * 256 + ntg * 16 + l15]);
    }
  } else if (tile < 320) {
    const int t = tile - 256, ks = t >> 3, ntg = t & 7;
#pragma unroll
    for (int e = 0; e < 8; ++e) {
      int k = ks * 32 + lg * 8 + e;
      w4f[(size_t)(t * 64 + l) * 8 + e] = to_f16u(uw2[k * 128 + ntg * 16 + l15]);
    }
  } else {
    const int t = tile - 320;            // 0..63: st = t>>2, ntile = t&3
    const int st = t >> 2, ntile = t & 3;
    const int lh = l >> 5, l31 = l & 31;
#pragma unroll
    for (int e = 0; e < 8; ++e) {
      int k = st * 16 + lh * 8 + e;
      bw2[(size_t)(t * 64 + l) * 8 + e] = to_f16u(mw2[k * 128 + ntile * 32 + l31]);
    }
  }
}

// ---------------- Kernel 1: LN*mask -> f16 + both projections, ONE block -------
// R25: merged halves. 256 blocks x 512 thr: LN once (32 thr/row, 16 rows),
// xh staged once; waves 0-3 -> xi_p (cols 0..255, f32), waves 4-7 -> xjh
// (cols 256..511 of mw1 == xj proj, f16).
__global__ __launch_bounds__(512) void k_ln_proj(
    const float* __restrict__ nodes, const float* __restrict__ node_mask,
    const float* __restrict__ ln_g, const float* __restrict__ ln_b,
    const unsigned short* __restrict__ w1f,
    float* __restrict__ xi_p, unsigned short* __restrict__ xjh) {
  const int row0 = blockIdx.x * 16;
  const int tid = threadIdx.x;
  __shared__ unsigned short xh[16 * 128];   // f16, 16B-group swizzled

  {
    const int r = tid >> 5, lane32 = tid & 31, c4 = lane32 * 4;
    float4 v = *(const float4*)(nodes + (size_t)(row0 + r) * D + c4);
    float s1 = v.x + v.y + v.z + v.w;
    float s2 = v.x * v.x + v.y * v.y + v.z * v.z + v.w * v.w;
#pragma unroll
    for (int off = 1; off < 32; off <<= 1) {
      s1 += __shfl_xor(s1, off);
      s2 += __shfl_xor(s2, off);
    }
    float mu = s1 * (1.0f / 128.0f);
    float var = s2 * (1.0f / 128.0f) - mu * mu;
    float rsig = rsqrtf(var + 1e-5f);
    float m = node_mask[row0 + r];
    float4 g4 = *(const float4*)(ln_g + c4);
    float4 b4 = *(const float4*)(ln_b + c4);
    float x0 = ((v.x - mu) * rsig * g4.x + b4.x) * m;
    float x1 = ((v.y - mu) * rsig * g4.y + b4.y) * m;
    float x2 = ((v.z - mu) * rsig * g4.z + b4.z) * m;
    float x3 = ((v.w - mu) * rsig * g4.w + b4.w) * m;
    uint2v u;
    u[0] = cvt_pk_f16(x0, x1);
    u[1] = cvt_pk_f16(x2, x3);
    const int g = (c4 >> 3) ^ (r & 7);    // swizzled 16B-group index
    *(uint2v*)(&xh[r * 128 + g * 8 + (c4 & 7)]) = u;
  }
  __syncthreads();

  const int w8 = tid >> 6, l = tid & 63;
  const int half = w8 >> 2, wq = w8 & 3;
  const int lg = l >> 4, l15 = l & 15;
  f32x4 acc[4];
#pragma unroll
  for (int nt = 0; nt < 4; ++nt) acc[nt] = (f32x4){0.f, 0.f, 0.f, 0.f};

#pragma unroll
  for (int ks = 0; ks < 4; ++ks) {
    const int g = (ks * 4 + lg) ^ (l15 & 7);
    f16x8 a = *(const f16x8*)(&xh[l15 * 128 + g * 8]);
#pragma unroll
    for (int nt = 0; nt < 4; ++nt) {
      const int tile = ks * 32 + half * 16 + wq * 4 + nt;
      f16x8 bf = *(const f16x8*)(w1f + (size_t)(tile * 64 + l) * 8);
      acc[nt] = __builtin_amdgcn_mfma_f32_16x16x32_f16(a, bf, acc[nt], 0, 0, 0);
    }
  }

  if (half == 0) {
#pragma unroll
    for (int nt = 0; nt < 4; ++nt)
#pragma unroll
      for (int r = 0; r < 4; ++r)
        xi_p[(size_t)(row0 + lg * 4 + r) * H + wq * 64 + nt * 16 + l15] = acc[nt][r];
  } else {
#pragma unroll
    for (int nt = 0; nt < 4; ++nt)
#pragma unroll
      for (int r = 0; r < 4; ++r)
        xjh[(size_t)(row0 + lg * 4 + r) * H + wq * 64 + nt * 16 + l15] = to_f16u(acc[nt][r]);
  }
}

// ---------------- Kernel 2: msgs GEMM (persistent) + FUSED update MLP ----------
// R25: csAll (all 16 i's packed xi+mb1 pairs, 8KB) staged ONCE per block --
// deletes per-item cs2 staging + 1 sync/item. Rest identical to R24 (41.7us
// R23 core + fused upd). LDS 153KB -> 1 block/CU, 16 waves. Tripwire: WRITE ~2MB.
__global__ __launch_bounds__(1024, 4) void k_msgs(
    const float* __restrict__ xi_p, const unsigned short* __restrict__ xjh,
    const unsigned short* __restrict__ bw2g, const float* __restrict__ mb1,
    const float* __restrict__ mb2, const float* __restrict__ node_mask,
    const float* __restrict__ nodes, const unsigned short* __restrict__ w3f,
    const float* __restrict__ ub1, const unsigned short* __restrict__ w4f,
    const float* __restrict__ ub2, float* __restrict__ out) {
  const int blk = blockIdx.x;
  const int b = blk >> 3;
  const int iq0 = (blk & 7) * 4;         // first i-quad of this block
  const int i16 = (blk & 7) * 16;        // first row of this block's 16
  const int tid = threadIdx.x;           // 0..1023
  const int w = tid >> 6, l = tid & 63;  // 16 waves
  const int ipair = w >> 3;              // 0..1
  const int jslab = (w & 7) >> 1;        // 0..3
  const int nh = w & 1;                  // 0..1
  const int jbase = jslab * 32;
  const int l31 = l & 31, lh = l >> 5;
  const int lg = (l >> 4) & 3, l15 = l & 15;

  __shared__ __align__(16) char smem[156672];  // 153 KB pool
  unsigned short* bw2s = (unsigned short*)smem;            // 64 KB
  unsigned short* xjs  = (unsigned short*)(smem + 65536);  // 64 KB
  unsigned* csAll      = (unsigned*)(smem + 131072);       // 8 KB [16][128]
  float* mb2s          = (float*)(smem + 139264);          // 512 B
  float* maskS         = (float*)(smem + 139776);          // 512 B
  float* waveAgg       = (float*)(smem + 140288);          // 8 KB [16][2][64]
  float* aggL          = (float*)(smem + 148480);          // 8 KB [16][128]
  // upd-phase overlay (xjs dead after main loop):
  unsigned short* ah   = (unsigned short*)(smem + 65536);  // 8 KB [16][256]
  unsigned short* uh   = (unsigned short*)(smem + 73728);  // 8 KB [16][256]
  float* nsf           = (float*)(smem + 81920);           // 8 KB [16][128]
  float* msk           = (float*)(smem + 90112);           // 64 B

  {
    const uint4v* src = (const uint4v*)bw2g;
    uint4v* dst = (uint4v*)bw2s;
#pragma unroll
    for (int c = 0; c < 4; ++c) dst[c * 1024 + tid] = src[c * 1024 + tid];
  }
  {
    // Stage xjh[b] (128 j x 256 k f16) into fragment-tile order (once per blk)
    const int jj = tid & 127;
    const int qq = tid >> 7;             // 0..7 -> chunks qq*4 .. qq*4+3
    const int js = jj >> 5, j31 = jj & 31;
    const unsigned short* grow = xjh + (size_t)(b * NN + jj) * H;
    uint4v* dst = (uint4v*)xjs;
#pragma unroll
    for (int r = 0; r < 4; ++r) {
      const int c = qq * 4 + r;          // 0..31
      const int st = c >> 1, lhh = c & 1;
      dst[((js * 16 + st) * 2 + lhh) * 32 + j31] =
          *(const uint4v*)(grow + c * 8);
    }
  }
  {
    // csAll: packed (xi_p + mb1) f16 pairs for this block's 16 i rows.
#pragma unroll
    for (int c = 0; c < 2; ++c) {
      int idx = c * 1024 + tid;          // 0..2047
      int ii = idx >> 7, p = idx & 127;
      float2 xi2 = *(const float2*)(xi_p + (size_t)(b * NN + i16 + ii) * H + 2 * p);
      float2 mbv = *(const float2*)(mb1 + 2 * p);
      csAll[ii * 128 + p] = cvt_pk_f16(xi2.x + mbv.x, xi2.y + mbv.y);
    }
  }
  if (tid < 128) { mb2s[tid] = mb2[tid]; maskS[tid] = node_mask[b * NN + tid]; }
  __syncthreads();

  const uint4v* bfrag = (const uint4v*)bw2s;
  const uint4v* xfrag = (const uint4v*)xjs;

  for (int t = 0; t < 4; ++t) {
    f32x16 acc[2][2];                    // [i-of-pair][ntile]
#pragma unroll
    for (int ii = 0; ii < 2; ++ii)
#pragma unroll
      for (int nt = 0; nt < 2; ++nt)
#pragma unroll
        for (int r = 0; r < 16; ++r) acc[ii][nt][r] = 0.f;

    const int ia = (t * 4 + ipair * 2) * 128;      // csAll row offsets
#pragma unroll
    for (int st = 0; st < 16; ++st) {
      const int kb = st * 16 + lh * 8;   // f16-elem k offset
      uint4v xu = xfrag[((jslab * 16 + st) * 2 + lh) * 32 + l31];
      uint4v cc0 = *(const uint4v*)(&csAll[ia + (kb >> 1)]);
      uint4v cc1 = *(const uint4v*)(&csAll[ia + 128 + (kb >> 1)]);
      uint4v a0, a1;
#pragma unroll
      for (int p = 0; p < 4; ++p) {
        a0[p] = pk_relu(pk_add_f16(xu[p], cc0[p]));
        a1[p] = pk_relu(pk_add_f16(xu[p], cc1[p]));
      }
      f16x8 af0 = __builtin_bit_cast(f16x8, a0);
      f16x8 af1 = __builtin_bit_cast(f16x8, a1);
#pragma unroll
      for (int nt = 0; nt < 2; ++nt) {
        f16x8 bf = __builtin_bit_cast(f16x8, bfrag[(st * 4 + nh * 2 + nt) * 64 + l]);
        acc[0][nt] = __builtin_amdgcn_mfma_f32_32x32x16_f16(af0, bf, acc[0][nt], 0, 0, 0);
        acc[1][nt] = __builtin_amdgcn_mfma_f32_32x32x16_f16(af1, bf, acc[1][nt], 0, 0, 0);
      }
    }

    // Epilogue: relu(acc+mb2)*mask_j, column-sum -> aggL (LDS).
#pragma unroll
    for (int ii = 0; ii < 2; ++ii)
#pragma unroll
      for (int nt = 0; nt < 2; ++nt) {
        const float bias = mb2s[nh * 64 + nt * 32 + l31];
        float s = 0.f;
#pragma unroll
        for (int reg = 0; reg < 16; ++reg) {
          const int j = jbase + 4 * lh + (reg & 3) + 8 * (reg >> 2);
          s = fmaf(fmaxf(acc[ii][nt][reg] + bias, 0.f), maskS[j], s);
        }
        s += __shfl_xor(s, 32);
        if (l < 32) waveAgg[((w * 2) + ii) * 64 + nt * 32 + l31] = s;
      }
    __syncthreads();
    if (tid < 512) {
      const int ii4 = tid >> 7, col = tid & 127;  // 4 i's x 128 cols
      const int ipq = ii4 >> 1, iwi = ii4 & 1;
      const int nh2 = col >> 6, c6 = col & 63;
      aggL[(t * 4 + ii4) * 128 + col] =
          waveAgg[((ipq * 8 + 0 + nh2) * 2 + iwi) * 64 + c6] +
          waveAgg[((ipq * 8 + 2 + nh2) * 2 + iwi) * 64 + c6] +
          waveAgg[((ipq * 8 + 4 + nh2) * 2 + iwi) * 64 + c6] +
          waveAgg[((ipq * 8 + 6 + nh2) * 2 + iwi) * 64 + c6];
    }
    __syncthreads();
  }

  // ---------- Fused update MLP for this block's 16 rows ----------
  if (tid < 256) {
    const int r = tid >> 4, l16 = tid & 15, d0 = l16 * 8;
    const size_t grow = (size_t)(b * NN + i16 + r) * D;
    float4 n0 = *(const float4*)(nodes + grow + d0);
    float4 n1 = *(const float4*)(nodes + grow + d0 + 4);
    *(float4*)(&nsf[r * 128 + d0]) = n0;
    *(float4*)(&nsf[r * 128 + d0 + 4]) = n1;
    uint4v u;
    u[0] = cvt_pk_f16(n0.x, n0.y); u[1] = cvt_pk_f16(n0.z, n0.w);
    u[2] = cvt_pk_f16(n1.x, n1.y); u[3] = cvt_pk_f16(n1.z, n1.w);
    int g = l16 ^ (r & 7);
    *(uint4v*)(&ah[r * 256 + g * 8]) = u;
    float4 a0 = *(const float4*)(&aggL[r * 128 + d0]);
    float4 a1 = *(const float4*)(&aggL[r * 128 + d0 + 4]);
    u[0] = cvt_pk_f16(a0.x, a0.y); u[1] = cvt_pk_f16(a0.z, a0.w);
    u[2] = cvt_pk_f16(a1.x, a1.y); u[3] = cvt_pk_f16(a1.z, a1.w);
    g = (16 + l16) ^ (r & 7);
    *(uint4v*)(&ah[r * 256 + g * 8]) = u;
    if (tid < 16) msk[tid] = node_mask[b * NN + i16 + tid];
  }
  __syncthreads();

  // GEMM1: 16x256, K=256; 16 waves, one 16-col tile each.
  {
    f32x4 acc3 = (f32x4){0.f, 0.f, 0.f, 0.f};
#pragma unroll
    for (int ks = 0; ks < 8; ++ks) {
      const int g = (ks * 4 + lg) ^ (l15 & 7);
      f16x8 a = *(const f16x8*)(&ah[l15 * 256 + g * 8]);
      f16x8 bf = *(const f16x8*)(w3f + (size_t)((ks * 16 + w) * 64 + l) * 8);
      acc3 = __builtin_amdgcn_mfma_f32_16x16x32_f16(a, bf, acc3, 0, 0, 0);
    }
    const int col = w * 16 + l15;
    const float bias = ub1[col];
#pragma unroll
    for (int r = 0; r < 4; ++r) {
      const int row = lg * 4 + r;
      const int g2 = (col >> 3) ^ (row & 7);
      uh[row * 256 + g2 * 8 + (col & 7)] = to_f16u(fmaxf(acc3[r] + bias, 0.f));
    }
  }
  __syncthreads();

  // GEMM2: 16x128, K=256; waves 0..7, one 16-col tile each.
  if (w < 8) {
    f32x4 acc4 = (f32x4){0.f, 0.f, 0.f, 0.f};
#pragma unroll
    for (int ks = 0; ks < 8; ++ks) {
      const int g = (ks * 4 + lg) ^ (l15 & 7);
      f16x8 a = *(const f16x8*)(&uh[l15 * 256 + g * 8]);
      f16x8 bf = *(const f16x8*)(w4f + (size_t)((ks * 8 + w) * 64 + l) * 8);
      acc4 = __builtin_amdgcn_mfma_f32_16x16x32_f16(a, bf, acc4, 0, 0, 0);
    }
    const int col = w * 16 + l15;
    const float ub2v = ub2[col];
#pragma unroll
    for (int r = 0; r < 4; ++r) {
      const int row = lg * 4 + r;
      out[(size_t)(b * NN + i16 + row) * D + col] =
          (nsf[row * 128 + col] + acc4[r] + ub2v) * msk[row];
    }
  }
}

extern "C" void kernel_launch(void* const* d_in, const int* in_sizes, int n_in,
                              void* d_out, int out_size, void* d_ws, size_t ws_size,
                              hipStream_t stream) {
  (void)in_sizes; (void)n_in; (void)out_size; (void)ws_size;
  const float* nodes     = (const float*)d_in[0];
  const float* node_mask = (const float*)d_in[1];
  const float* ln_g      = (const float*)d_in[2];
  const float* ln_b      = (const float*)d_in[3];
  const float* mw1       = (const float*)d_in[4];
  const float* mb1       = (const float*)d_in[5];
  const float* mw2       = (const float*)d_in[6];
  const float* mb2       = (const float*)d_in[7];
  const float* uw1       = (const float*)d_in[8];
  const float* ub1       = (const float*)d_in[9];
  const float* uw2       = (const float*)d_in[10];
  const float* ub2       = (const float*)d_in[11];
  float* out = (float*)d_out;

  char* ws = (char*)d_ws;
  float*          xi_p = (float*)(ws);                               // 4 MB
  unsigned short* xjh  = (unsigned short*)(ws + ((size_t)4 << 20));  // 2 MB
  unsigned short* bw2  = (unsigned short*)(ws + ((size_t)6 << 20));            // 64 KB
  unsigned short* w1f  = (unsigned short*)(ws + ((size_t)6 << 20) + (64 << 10));   // 128 KB
  unsigned short* w3f  = (unsigned short*)(ws + ((size_t)6 << 20) + (192 << 10));  // 128 KB
  unsigned short* w4f  = (unsigned short*)(ws + ((size_t)6 << 20) + (320 << 10));  // 64 KB

  k_repack<<<48, 512, 0, stream>>>(mw1, uw1, uw2, mw2, w1f, w3f, w4f, bw2);
  k_ln_proj<<<256, 512, 0, stream>>>(nodes, node_mask, ln_g, ln_b, w1f, xi_p, xjh);
  k_msgs<<<256, 1024, 0, stream>>>(xi_p, xjh, bw2, mb1, mb2, node_mask,
                                   nodes, w3f, ub1, w4f, ub2, out);
}